// Round 2
// baseline (3093.072 us; speedup 1.0000x reference)
//
#include <hip/hip_runtime.h>

// Problem constants (from reference)
constexpr int NNODES = 50000;
constexpr int NEDGES = 600000;
constexpr int NGRAPH = 2000;
constexpr int F0     = 64;    // IN_FEATS
constexpr int H      = 128;   // HIDDEN
constexpr int H2     = 256;   // 2*HIDDEN

// ---------------- degree count ----------------
__global__ void k_deg(const int* __restrict__ src, const int* __restrict__ dst,
                      float* __restrict__ dout, float* __restrict__ din) {
    int e = blockIdx.x * 256 + threadIdx.x;
    if (e < NEDGES) {
        atomicAdd(&dout[src[e]], 1.0f);
        atomicAdd(&din[dst[e]], 1.0f);
    }
}

// in-place: deg -> rsqrt(max(deg,1))
__global__ void k_cnorm(float* __restrict__ c_out, float* __restrict__ c_in) {
    int n = blockIdx.x * 256 + threadIdx.x;
    if (n < NNODES) {
        c_out[n] = rsqrtf(fmaxf(c_out[n], 1.0f));
        c_in[n]  = rsqrtf(fmaxf(c_in[n], 1.0f));
    }
}

// ---------------- edge scatter: agg[dst] += x[src] * c_out[src] ----------------
template <int F>
__global__ void k_scatter(const float* __restrict__ x, const float* __restrict__ c_out,
                          const int* __restrict__ src, const int* __restrict__ dst,
                          float* __restrict__ agg) {
    constexpr int Q = F / 4;           // float4 groups per row
    int gid = blockIdx.x * 256 + threadIdx.x;
    int e = gid / Q;
    int q = gid - e * Q;
    if (e < NEDGES) {
        int s = src[e], d = dst[e];
        float co = c_out[s];
        float4 v = ((const float4*)x)[(long)s * Q + q];
        float* a = agg + (long)d * F + q * 4;
        atomicAdd(a + 0, v.x * co);
        atomicAdd(a + 1, v.y * co);
        atomicAdd(a + 2, v.z * co);
        atomicAdd(a + 3, v.w * co);
    }
}

// ---------------- fused node GEMM: out = act( c_in * (A @ W) + b ) ----------------
// A: [N, K], W: [K, 128], out: [N, 128]. 32 rows per block, W staged in LDS.
template <int K, bool RELU>
__global__ __launch_bounds__(256) void k_gemm(const float* __restrict__ A,
                                              const float* __restrict__ c_in,
                                              const float* __restrict__ W,
                                              const float* __restrict__ b,
                                              float* __restrict__ out) {
    __shared__ float sW[K * H];
    for (int i = threadIdx.x; i < K * H / 4; i += 256)
        ((float4*)sW)[i] = ((const float4*)W)[i];
    __syncthreads();

    int j    = threadIdx.x & 127;   // output column
    int half = threadIdx.x >> 7;    // 0 or 1
    int base = blockIdx.x * 32;
    float bj = b[j];

    for (int it = 0; it < 16; ++it) {
        int n = base + it * 2 + half;
        if (n >= NNODES) break;
        float ci = c_in[n];
        const float4* Av = (const float4*)(A + (long)n * K);
        float sum = 0.0f;
#pragma unroll
        for (int k4 = 0; k4 < K / 4; ++k4) {
            float4 a = Av[k4];
            sum += a.x * sW[(k4 * 4 + 0) * H + j];
            sum += a.y * sW[(k4 * 4 + 1) * H + j];
            sum += a.z * sW[(k4 * 4 + 2) * H + j];
            sum += a.w * sW[(k4 * 4 + 3) * H + j];
        }
        float r = sum * ci + bj;
        if (RELU) r = fmaxf(r, 0.0f);
        out[(long)n * H + j] = r;
    }
}

// ---------------- graph readout: gsum[g] += y[n], gcnt[g] += 1 ----------------
__global__ void k_readout(const float* __restrict__ y, const int* __restrict__ gids,
                          float* __restrict__ gsum, float* __restrict__ gcnt) {
    int gid = blockIdx.x * 256 + threadIdx.x;
    int n = gid >> 7, j = gid & 127;
    if (n < NNODES) {
        int g = gids[n];
        atomicAdd(&gsum[g * H + j], y[(long)n * H + j]);
        if (j == 0) atomicAdd(&gcnt[g], 1.0f);
    }
}

// ---------------- MLP layer 1: [G,131] @ [131,256] + relu ----------------
__global__ void k_mlp1(const float* __restrict__ gsum, const float* __restrict__ gcnt,
                       const float* __restrict__ fg, const float* __restrict__ Wl1,
                       const float* __restrict__ bl1, float* __restrict__ h1) {
    int gid = blockIdx.x * 256 + threadIdx.x;
    int g = gid >> 8, j = gid & 255;
    if (g >= NGRAPH) return;
    float inv = 1.0f / fmaxf(gcnt[g], 1.0f);
    float sum = bl1[j];
    for (int k = 0; k < H; ++k)
        sum += gsum[g * H + k] * inv * Wl1[k * H2 + j];
    for (int k = 0; k < 3; ++k)
        sum += fg[g * 3 + k] * Wl1[(H + k) * H2 + j];
    h1[g * H2 + j] = fmaxf(sum, 0.0f);
}

// ---------------- MLP layer 2: [G,256] @ [256,256] + relu ----------------
__global__ void k_mlp2(const float* __restrict__ h1, const float* __restrict__ Wl2,
                       const float* __restrict__ bl2, float* __restrict__ h2) {
    int gid = blockIdx.x * 256 + threadIdx.x;
    int g = gid >> 8, j = gid & 255;
    if (g >= NGRAPH) return;
    float sum = bl2[j];
    for (int k = 0; k < H2; ++k)
        sum += h1[g * H2 + k] * Wl2[k * H2 + j];
    h2[g * H2 + j] = fmaxf(sum, 0.0f);
}

// ---------------- MLP layer 3: [G,256] @ [256,1] -> out[G] ----------------
__global__ void k_mlp3(const float* __restrict__ h2, const float* __restrict__ Wl3,
                       const float* __restrict__ bl3, float* __restrict__ out) {
    int gw = (blockIdx.x * 256 + threadIdx.x) >> 6;
    int lane = threadIdx.x & 63;
    if (gw >= NGRAPH) return;
    float sum = 0.0f;
    for (int k = lane; k < H2; k += 64)
        sum += h2[gw * H2 + k] * Wl3[k];
    for (int off = 32; off; off >>= 1)
        sum += __shfl_down(sum, off);
    if (lane == 0) out[gw] = sum + bl3[0];
}

extern "C" void kernel_launch(void* const* d_in, const int* in_sizes, int n_in,
                              void* d_out, int out_size, void* d_ws, size_t ws_size,
                              hipStream_t stream) {
    const float* feats_node = (const float*)d_in[0];
    const float* feats_graph = (const float*)d_in[1];
    const float* W1 = (const float*)d_in[2];
    const float* b1 = (const float*)d_in[3];
    const float* W2 = (const float*)d_in[4];
    const float* b2 = (const float*)d_in[5];
    const float* W3 = (const float*)d_in[6];
    const float* b3 = (const float*)d_in[7];
    const float* Wl1 = (const float*)d_in[8];
    const float* bl1 = (const float*)d_in[9];
    const float* Wl2 = (const float*)d_in[10];
    const float* bl2 = (const float*)d_in[11];
    const float* Wl3 = (const float*)d_in[12];
    const float* bl3 = (const float*)d_in[13];
    const int* src = (const int*)d_in[14];
    const int* dst = (const int*)d_in[15];
    const int* gids = (const int*)d_in[16];
    float* out = (float*)d_out;

    // workspace layout (floats)
    float* ws = (float*)d_ws;
    const size_t OFF_COUT = 0;                       // 50048
    const size_t OFF_CIN  = 50048;                   // 50048
    const size_t OFF_A    = 100096;                  // N*H
    const size_t OFF_B    = OFF_A + (size_t)NNODES * H;   // N*H
    const size_t OFF_GSUM = OFF_B + (size_t)NNODES * H;   // G*H
    const size_t OFF_GCNT = OFF_GSUM + (size_t)NGRAPH * H; // 2048 pad
    const size_t OFF_H1   = OFF_GCNT + 2048;         // G*H2
    const size_t OFF_H2   = OFF_H1 + (size_t)NGRAPH * H2;
    float* c_out = ws + OFF_COUT;
    float* c_in  = ws + OFF_CIN;
    float* A     = ws + OFF_A;
    float* B     = ws + OFF_B;
    float* gsum  = ws + OFF_GSUM;
    float* gcnt  = ws + OFF_GCNT;
    float* h1    = ws + OFF_H1;
    float* h2    = ws + OFF_H2;

    // degrees -> c_out / c_in
    hipMemsetAsync(c_out, 0, 2 * 50048 * sizeof(float), stream);
    k_deg<<<(NEDGES + 255) / 256, 256, 0, stream>>>(src, dst, c_out, c_in);
    k_cnorm<<<(NNODES + 255) / 256, 256, 0, stream>>>(c_out, c_in);

    // layer 1: scatter feats (F=64) -> A, gemm -> B
    hipMemsetAsync(A, 0, (size_t)NNODES * F0 * sizeof(float), stream);
    k_scatter<F0><<<(NEDGES * (F0 / 4) + 255) / 256, 256, 0, stream>>>(
        feats_node, c_out, src, dst, A);
    k_gemm<F0, true><<<(NNODES + 31) / 32, 256, 0, stream>>>(A, c_in, W1, b1, B);

    // layer 2: scatter B (F=128) -> A, gemm -> B
    hipMemsetAsync(A, 0, (size_t)NNODES * H * sizeof(float), stream);
    k_scatter<H><<<(NEDGES * (H / 4) + 255) / 256, 256, 0, stream>>>(
        B, c_out, src, dst, A);
    k_gemm<H, true><<<(NNODES + 31) / 32, 256, 0, stream>>>(A, c_in, W2, b2, B);

    // layer 3: scatter B -> A, gemm (no relu) -> B
    hipMemsetAsync(A, 0, (size_t)NNODES * H * sizeof(float), stream);
    k_scatter<H><<<(NEDGES * (H / 4) + 255) / 256, 256, 0, stream>>>(
        B, c_out, src, dst, A);
    k_gemm<H, false><<<(NNODES + 31) / 32, 256, 0, stream>>>(A, c_in, W3, b3, B);

    // readout mean
    hipMemsetAsync(gsum, 0, ((size_t)NGRAPH * H + 2048) * sizeof(float), stream);
    k_readout<<<((size_t)NNODES * H + 255) / 256, 256, 0, stream>>>(B, gids, gsum, gcnt);

    // MLP head
    k_mlp1<<<(NGRAPH * H2 + 255) / 256, 256, 0, stream>>>(gsum, gcnt, feats_graph, Wl1, bl1, h1);
    k_mlp2<<<(NGRAPH * H2 + 255) / 256, 256, 0, stream>>>(h1, Wl2, bl2, h2);
    k_mlp3<<<(NGRAPH * 64 + 255) / 256, 256, 0, stream>>>(h2, Wl3, bl3, out);
}

// Round 3
// 765.260 us; speedup vs baseline: 4.0419x; 4.0419x over previous
//
#include <hip/hip_runtime.h>

constexpr int NNODES = 50000;
constexpr int NEDGES = 600000;
constexpr int NGRAPH = 2000;
constexpr int F0     = 64;    // IN_FEATS
constexpr int H      = 128;   // HIDDEN
constexpr int H2     = 256;   // 2*HIDDEN

// ---------------- degree count (float atomics into c_out/c_in slots) ----------------
__global__ void k_deg(const int* __restrict__ src, const int* __restrict__ dst,
                      float* __restrict__ dout, float* __restrict__ din) {
    int e = blockIdx.x * 256 + threadIdx.x;
    if (e < NEDGES) {
        atomicAdd(&dout[src[e]], 1.0f);
        atomicAdd(&din[dst[e]], 1.0f);
    }
}

// exclusive prefix scan of deg_in (read as float, exact for small ints) -> row_start
__global__ __launch_bounds__(1024) void k_scan(const float* __restrict__ degf,
                                               int* __restrict__ row_start) {
    __shared__ int part[1024];
    const int CHUNK = 49;  // 1024*49 = 50176 >= 50000
    int t = threadIdx.x;
    int base = t * CHUNK;
    int s = 0;
    for (int i = 0; i < CHUNK; ++i) {
        int idx = base + i;
        if (idx < NNODES) s += (int)degf[idx];
    }
    part[t] = s;
    __syncthreads();
    for (int off = 1; off < 1024; off <<= 1) {
        int v = (t >= off) ? part[t - off] : 0;
        __syncthreads();
        part[t] += v;
        __syncthreads();
    }
    int run = (t == 0) ? 0 : part[t - 1];
    for (int i = 0; i < CHUNK; ++i) {
        int idx = base + i;
        if (idx < NNODES) {
            row_start[idx] = run;
            run += (int)degf[idx];
        }
    }
    if (t == 1023) row_start[NNODES] = run;
}

// fill CSR: csr_src[row_start[dst] + cursor[dst]++] = src
__global__ void k_fill(const int* __restrict__ src, const int* __restrict__ dst,
                       const int* __restrict__ row_start, int* __restrict__ cursor,
                       int* __restrict__ csr_src) {
    int e = blockIdx.x * 256 + threadIdx.x;
    if (e < NEDGES) {
        int d = dst[e];
        int p = atomicAdd(&cursor[d], 1);
        csr_src[row_start[d] + p] = src[e];
    }
}

// deg -> rsqrt(max(deg,1))
__global__ void k_cnorm(float* __restrict__ c_out, float* __restrict__ c_in) {
    int n = blockIdx.x * 256 + threadIdx.x;
    if (n < NNODES) {
        c_out[n] = rsqrtf(fmaxf(c_out[n], 1.0f));
        c_in[n]  = rsqrtf(fmaxf(c_in[n], 1.0f));
    }
}

// graph segment boundaries from sorted graph_ids
__global__ void k_gbounds(const int* __restrict__ gids, int* __restrict__ gstart) {
    int n = blockIdx.x * 256 + threadIdx.x;
    if (n > NNODES) return;
    if (n == 0) {
        int g0 = gids[0];
        for (int g = 0; g <= g0; ++g) gstart[g] = 0;
    } else if (n == NNODES) {
        int gl = gids[NNODES - 1];
        for (int g = gl + 1; g <= NGRAPH; ++g) gstart[g] = NNODES;
    } else {
        int a = gids[n - 1], b = gids[n];
        for (int g = a + 1; g <= b; ++g) gstart[g] = n;
    }
}

// ---------------- gather aggregation: agg[n] = sum_{e in CSR[n]} x[src_e]*c_out[src_e] ----------------
// one wave per dst node; lanes split the feature row
template <int F>
__global__ __launch_bounds__(256) void k_gather(const float* __restrict__ x,
                                                const float* __restrict__ c_out,
                                                const int* __restrict__ row_start,
                                                const int* __restrict__ csr_src,
                                                float* __restrict__ agg) {
    int wid  = (blockIdx.x * 256 + threadIdx.x) >> 6;
    int lane = threadIdx.x & 63;
    if (wid >= NNODES) return;
    int beg = row_start[wid], end = row_start[wid + 1];
    if (F == 128) {
        const float2* x2 = (const float2*)x;
        float2 acc = make_float2(0.f, 0.f);
#pragma unroll 2
        for (int i = beg; i < end; ++i) {
            int s = csr_src[i];
            float co = c_out[s];
            float2 v = x2[(long)s * 64 + lane];
            acc.x += v.x * co;
            acc.y += v.y * co;
        }
        ((float2*)agg)[(long)wid * 64 + lane] = acc;
    } else {
        float acc = 0.f;
#pragma unroll 2
        for (int i = beg; i < end; ++i) {
            int s = csr_src[i];
            acc += x[(long)s * F + lane] * c_out[s];
        }
        agg[(long)wid * F + lane] = acc;
    }
}

// ---------------- fused node GEMM: out = act( c_in * (A @ W) + b ) ----------------
template <int K, bool RELU>
__global__ __launch_bounds__(256) void k_gemm(const float* __restrict__ A,
                                              const float* __restrict__ c_in,
                                              const float* __restrict__ W,
                                              const float* __restrict__ b,
                                              float* __restrict__ out) {
    __shared__ float sW[K * H];
    for (int i = threadIdx.x; i < K * H / 4; i += 256)
        ((float4*)sW)[i] = ((const float4*)W)[i];
    __syncthreads();

    int j    = threadIdx.x & 127;
    int half = threadIdx.x >> 7;
    int base = blockIdx.x * 32;
    float bj = b[j];

    for (int it = 0; it < 16; ++it) {
        int n = base + it * 2 + half;
        if (n >= NNODES) break;
        float ci = c_in[n];
        const float4* Av = (const float4*)(A + (long)n * K);
        float sum = 0.0f;
#pragma unroll
        for (int k4 = 0; k4 < K / 4; ++k4) {
            float4 a = Av[k4];
            sum += a.x * sW[(k4 * 4 + 0) * H + j];
            sum += a.y * sW[(k4 * 4 + 1) * H + j];
            sum += a.z * sW[(k4 * 4 + 2) * H + j];
            sum += a.w * sW[(k4 * 4 + 3) * H + j];
        }
        float r = sum * ci + bj;
        if (RELU) r = fmaxf(r, 0.0f);
        out[(long)n * H + j] = r;
    }
}

// ---------------- segment-mean readout (contiguous node ranges) ----------------
__global__ void k_readout(const float* __restrict__ y, const int* __restrict__ gstart,
                          float* __restrict__ mean) {
    int g    = (blockIdx.x * 256 + threadIdx.x) >> 6;
    int lane = threadIdx.x & 63;
    if (g >= NGRAPH) return;
    int beg = gstart[g], end = gstart[g + 1];
    const float2* y2 = (const float2*)y;
    float2 acc = make_float2(0.f, 0.f);
    for (int n = beg; n < end; ++n) {
        float2 v = y2[(long)n * 64 + lane];
        acc.x += v.x;
        acc.y += v.y;
    }
    float inv = 1.0f / fmaxf((float)(end - beg), 1.0f);
    ((float2*)mean)[(long)g * 64 + lane] = make_float2(acc.x * inv, acc.y * inv);
}

// ---------------- MLP head ----------------
__global__ void k_mlp1(const float* __restrict__ mean, const float* __restrict__ fg,
                       const float* __restrict__ Wl1, const float* __restrict__ bl1,
                       float* __restrict__ h1) {
    int gid = blockIdx.x * 256 + threadIdx.x;
    int g = gid >> 8, j = gid & 255;
    if (g >= NGRAPH) return;
    float sum = bl1[j];
    for (int k = 0; k < H; ++k)
        sum += mean[g * H + k] * Wl1[k * H2 + j];
    for (int k = 0; k < 3; ++k)
        sum += fg[g * 3 + k] * Wl1[(H + k) * H2 + j];
    h1[g * H2 + j] = fmaxf(sum, 0.0f);
}

__global__ void k_mlp2(const float* __restrict__ h1, const float* __restrict__ Wl2,
                       const float* __restrict__ bl2, float* __restrict__ h2) {
    int gid = blockIdx.x * 256 + threadIdx.x;
    int g = gid >> 8, j = gid & 255;
    if (g >= NGRAPH) return;
    float sum = bl2[j];
    for (int k = 0; k < H2; ++k)
        sum += h1[g * H2 + k] * Wl2[k * H2 + j];
    h2[g * H2 + j] = fmaxf(sum, 0.0f);
}

__global__ void k_mlp3(const float* __restrict__ h2, const float* __restrict__ Wl3,
                       const float* __restrict__ bl3, float* __restrict__ out) {
    int gw = (blockIdx.x * 256 + threadIdx.x) >> 6;
    int lane = threadIdx.x & 63;
    if (gw >= NGRAPH) return;
    float sum = 0.0f;
    for (int k = lane; k < H2; k += 64)
        sum += h2[gw * H2 + k] * Wl3[k];
    for (int off = 32; off; off >>= 1)
        sum += __shfl_down(sum, off);
    if (lane == 0) out[gw] = sum + bl3[0];
}

extern "C" void kernel_launch(void* const* d_in, const int* in_sizes, int n_in,
                              void* d_out, int out_size, void* d_ws, size_t ws_size,
                              hipStream_t stream) {
    const float* feats_node  = (const float*)d_in[0];
    const float* feats_graph = (const float*)d_in[1];
    const float* W1 = (const float*)d_in[2];
    const float* b1 = (const float*)d_in[3];
    const float* W2 = (const float*)d_in[4];
    const float* b2 = (const float*)d_in[5];
    const float* W3 = (const float*)d_in[6];
    const float* b3 = (const float*)d_in[7];
    const float* Wl1 = (const float*)d_in[8];
    const float* bl1 = (const float*)d_in[9];
    const float* Wl2 = (const float*)d_in[10];
    const float* bl2 = (const float*)d_in[11];
    const float* Wl3 = (const float*)d_in[12];
    const float* bl3 = (const float*)d_in[13];
    const int* src  = (const int*)d_in[14];
    const int* dst  = (const int*)d_in[15];
    const int* gids = (const int*)d_in[16];
    float* out = (float*)d_out;

    // workspace layout (float/int units of 4B)
    float* ws = (float*)d_ws;
    float* c_out     = ws;                        // 50048
    float* c_in      = c_out + 50048;             // 50048
    float* A         = c_in + 50048;              // 6,400,000
    float* B         = A + (size_t)NNODES * H;    // 6,400,000
    int*   row_start = (int*)(B + (size_t)NNODES * H);  // 50176
    int*   csr_src   = row_start + 50176;         // 600,000
    int*   cursor    = csr_src + NEDGES;          // 50176
    int*   gstart    = cursor + 50176;            // 2048
    float* mean      = (float*)(gstart + 2048);   // 256,000
    float* h1        = mean + (size_t)NGRAPH * H; // 512,000
    float* h2        = h1 + (size_t)NGRAPH * H2;  // 512,000

    // degrees (as float counts in c_out/c_in)
    hipMemsetAsync(c_out, 0, 2 * 50048 * sizeof(float), stream);
    k_deg<<<(NEDGES + 255) / 256, 256, 0, stream>>>(src, dst, c_out, c_in);

    // CSR build from deg_in (c_in), then normalize degrees
    k_scan<<<1, 1024, 0, stream>>>(c_in, row_start);
    hipMemsetAsync(cursor, 0, 50176 * sizeof(int), stream);
    k_fill<<<(NEDGES + 255) / 256, 256, 0, stream>>>(src, dst, row_start, cursor, csr_src);
    k_cnorm<<<(NNODES + 255) / 256, 256, 0, stream>>>(c_out, c_in);
    k_gbounds<<<(NNODES + 256) / 256, 256, 0, stream>>>(gids, gstart);

    // layer 1: gather feats (F=64) -> A, gemm -> B
    k_gather<F0><<<NNODES / 4, 256, 0, stream>>>(feats_node, c_out, row_start, csr_src, A);
    k_gemm<F0, true><<<(NNODES + 31) / 32, 256, 0, stream>>>(A, c_in, W1, b1, B);

    // layer 2
    k_gather<H><<<NNODES / 4, 256, 0, stream>>>(B, c_out, row_start, csr_src, A);
    k_gemm<H, true><<<(NNODES + 31) / 32, 256, 0, stream>>>(A, c_in, W2, b2, B);

    // layer 3 (no relu)
    k_gather<H><<<NNODES / 4, 256, 0, stream>>>(B, c_out, row_start, csr_src, A);
    k_gemm<H, false><<<(NNODES + 31) / 32, 256, 0, stream>>>(A, c_in, W3, b3, B);

    // readout mean (contiguous segments)
    k_readout<<<(NGRAPH * 64 + 255) / 256, 256, 0, stream>>>(B, gstart, mean);

    // MLP head
    k_mlp1<<<(NGRAPH * H2 + 255) / 256, 256, 0, stream>>>(mean, feats_graph, Wl1, bl1, h1);
    k_mlp2<<<(NGRAPH * H2 + 255) / 256, 256, 0, stream>>>(h1, Wl2, bl2, h2);
    k_mlp3<<<(NGRAPH * 64 + 255) / 256, 256, 0, stream>>>(h2, Wl3, bl3, out);
}

// Round 4
// 543.304 us; speedup vs baseline: 5.6931x; 1.4085x over previous
//
#include <hip/hip_runtime.h>

constexpr int NNODES = 50000;
constexpr int NEDGES = 600000;
constexpr int NGRAPH = 2000;
constexpr int F0     = 64;    // IN_FEATS
constexpr int H      = 128;   // HIDDEN
constexpr int H2     = 256;   // 2*HIDDEN

static __device__ __forceinline__ void fma4(float4& acc, float s, const float4& w) {
    acc.x = fmaf(s, w.x, acc.x);
    acc.y = fmaf(s, w.y, acc.y);
    acc.z = fmaf(s, w.z, acc.z);
    acc.w = fmaf(s, w.w, acc.w);
}

// ---------------- degree count ----------------
__global__ void k_deg(const int* __restrict__ src, const int* __restrict__ dst,
                      float* __restrict__ dout, float* __restrict__ din) {
    int e = blockIdx.x * 256 + threadIdx.x;
    if (e < NEDGES) {
        atomicAdd(&dout[src[e]], 1.0f);
        atomicAdd(&din[dst[e]], 1.0f);
    }
}

// exclusive prefix scan of deg_in -> row_start
__global__ __launch_bounds__(1024) void k_scan(const float* __restrict__ degf,
                                               int* __restrict__ row_start) {
    __shared__ int part[1024];
    const int CHUNK = 49;  // 1024*49 >= 50000
    int t = threadIdx.x;
    int base = t * CHUNK;
    int s = 0;
    for (int i = 0; i < CHUNK; ++i) {
        int idx = base + i;
        if (idx < NNODES) s += (int)degf[idx];
    }
    part[t] = s;
    __syncthreads();
    for (int off = 1; off < 1024; off <<= 1) {
        int v = (t >= off) ? part[t - off] : 0;
        __syncthreads();
        part[t] += v;
        __syncthreads();
    }
    int run = (t == 0) ? 0 : part[t - 1];
    for (int i = 0; i < CHUNK; ++i) {
        int idx = base + i;
        if (idx < NNODES) {
            row_start[idx] = run;
            run += (int)degf[idx];
        }
    }
    if (t == 1023) row_start[NNODES] = run;
}

// fill CSR
__global__ void k_fill(const int* __restrict__ src, const int* __restrict__ dst,
                       const int* __restrict__ row_start, int* __restrict__ cursor,
                       int* __restrict__ csr_src) {
    int e = blockIdx.x * 256 + threadIdx.x;
    if (e < NEDGES) {
        int d = dst[e];
        int p = atomicAdd(&cursor[d], 1);
        csr_src[row_start[d] + p] = src[e];
    }
}

// deg -> rsqrt(max(deg,1))
__global__ void k_cnorm(float* __restrict__ c_out, float* __restrict__ c_in) {
    int n = blockIdx.x * 256 + threadIdx.x;
    if (n < NNODES) {
        c_out[n] = rsqrtf(fmaxf(c_out[n], 1.0f));
        c_in[n]  = rsqrtf(fmaxf(c_in[n], 1.0f));
    }
}

// graph segment boundaries from sorted graph_ids
__global__ void k_gbounds(const int* __restrict__ gids, int* __restrict__ gstart) {
    int n = blockIdx.x * 256 + threadIdx.x;
    if (n > NNODES) return;
    if (n == 0) {
        int g0 = gids[0];
        for (int g = 0; g <= g0; ++g) gstart[g] = 0;
    } else if (n == NNODES) {
        int gl = gids[NNODES - 1];
        for (int g = gl + 1; g <= NGRAPH; ++g) gstart[g] = NNODES;
    } else {
        int a = gids[n - 1], b = gids[n];
        for (int g = a + 1; g <= b; ++g) gstart[g] = n;
    }
}

// ---------------- gather aggregation ----------------
template <int F>
__global__ __launch_bounds__(256) void k_gather(const float* __restrict__ x,
                                                const float* __restrict__ c_out,
                                                const int* __restrict__ row_start,
                                                const int* __restrict__ csr_src,
                                                float* __restrict__ agg) {
    int wid  = (blockIdx.x * 256 + threadIdx.x) >> 6;
    int lane = threadIdx.x & 63;
    if (wid >= NNODES) return;
    int beg = row_start[wid], end = row_start[wid + 1];
    if (F == 128) {
        const float2* x2 = (const float2*)x;
        float2 acc = make_float2(0.f, 0.f);
#pragma unroll 4
        for (int i = beg; i < end; ++i) {
            int s = csr_src[i];
            float co = c_out[s];
            float2 v = x2[(long)s * 64 + lane];
            acc.x += v.x * co;
            acc.y += v.y * co;
        }
        ((float2*)agg)[(long)wid * 64 + lane] = acc;
    } else {
        float acc = 0.f;
#pragma unroll 4
        for (int i = beg; i < end; ++i) {
            int s = csr_src[i];
            acc += x[(long)s * F + lane] * c_out[s];
        }
        agg[(long)wid * F + lane] = acc;
    }
}

// ---------------- register-blocked fused GEMM ----------------
// out[n][j] = act( c_in[n] * sum_k A[n][k] W[k][j] + b[j] )
// 512 threads, 128-row tile, thread = 8 rows x 4 cols.
template <int K, bool RELU>
__global__ __launch_bounds__(512) void k_gemm(const float* __restrict__ A,
                                              const float* __restrict__ c_in,
                                              const float* __restrict__ W,
                                              const float* __restrict__ b,
                                              float* __restrict__ out) {
    __shared__ float sW[K * H];
    for (int i = threadIdx.x; i < K * (H / 4); i += 512)
        ((float4*)sW)[i] = ((const float4*)W)[i];
    __syncthreads();

    const int c = threadIdx.x & 31;   // col quad: cols 4c..4c+3
    const int r = threadIdx.x >> 5;   // row octet: 8 rows
    const long base = (long)blockIdx.x * 128 + r * 8;

    float4 acc[8];
#pragma unroll
    for (int i = 0; i < 8; ++i) acc[i] = make_float4(0.f, 0.f, 0.f, 0.f);

    const float4* Ap = (const float4*)A + base * (K / 4);

    for (int k4 = 0; k4 < K / 4; ++k4) {
        const float4 w0 = *(const float4*)&sW[(4 * k4 + 0) * H + 4 * c];
        const float4 w1 = *(const float4*)&sW[(4 * k4 + 1) * H + 4 * c];
        const float4 w2 = *(const float4*)&sW[(4 * k4 + 2) * H + 4 * c];
        const float4 w3 = *(const float4*)&sW[(4 * k4 + 3) * H + 4 * c];
#pragma unroll
        for (int i = 0; i < 8; ++i) {
            float4 a = Ap[(long)i * (K / 4) + k4];
            fma4(acc[i], a.x, w0);
            fma4(acc[i], a.y, w1);
            fma4(acc[i], a.z, w2);
            fma4(acc[i], a.w, w3);
        }
    }

    const float4 bv = ((const float4*)b)[c];
#pragma unroll
    for (int i = 0; i < 8; ++i) {
        long n = base + i;
        if (n < NNODES) {
            float ci = c_in[n];
            float4 res;
            res.x = fmaf(acc[i].x, ci, bv.x);
            res.y = fmaf(acc[i].y, ci, bv.y);
            res.z = fmaf(acc[i].z, ci, bv.z);
            res.w = fmaf(acc[i].w, ci, bv.w);
            if (RELU) {
                res.x = fmaxf(res.x, 0.f);
                res.y = fmaxf(res.y, 0.f);
                res.z = fmaxf(res.z, 0.f);
                res.w = fmaxf(res.w, 0.f);
            }
            ((float4*)out)[n * (H / 4) + c] = res;
        }
    }
}

// ---------------- segment-mean readout (2 graphs per block) ----------------
__global__ void k_readout(const float* __restrict__ y, const int* __restrict__ gstart,
                          float* __restrict__ mean) {
    int g = blockIdx.x * 2 + (threadIdx.x >> 7);
    int j = threadIdx.x & 127;
    if (g >= NGRAPH) return;
    int beg = gstart[g], end = gstart[g + 1];
    float acc = 0.f;
    for (int n = beg; n < end; ++n) acc += y[(long)n * H + j];
    mean[g * H + j] = acc / fmaxf((float)(end - beg), 1.0f);
}

// ---------------- MLP head (quad-column vectorized) ----------------
__global__ void k_mlp1(const float* __restrict__ mean, const float* __restrict__ fg,
                       const float* __restrict__ Wl1, const float* __restrict__ bl1,
                       float* __restrict__ h1) {
    int g  = blockIdx.x * 4 + (threadIdx.x >> 6);
    int jq = threadIdx.x & 63;
    if (g >= NGRAPH) return;
    float4 acc = ((const float4*)bl1)[jq];
    for (int k = 0; k < H; ++k)
        fma4(acc, mean[g * H + k], ((const float4*)(Wl1 + (long)k * H2))[jq]);
    for (int k = 0; k < 3; ++k)
        fma4(acc, fg[g * 3 + k], ((const float4*)(Wl1 + (long)(H + k) * H2))[jq]);
    acc.x = fmaxf(acc.x, 0.f); acc.y = fmaxf(acc.y, 0.f);
    acc.z = fmaxf(acc.z, 0.f); acc.w = fmaxf(acc.w, 0.f);
    ((float4*)h1)[g * 64 + jq] = acc;
}

__global__ void k_mlp2(const float* __restrict__ h1, const float* __restrict__ Wl2,
                       const float* __restrict__ bl2, float* __restrict__ h2) {
    int g  = blockIdx.x * 4 + (threadIdx.x >> 6);
    int jq = threadIdx.x & 63;
    if (g >= NGRAPH) return;
    float4 acc = ((const float4*)bl2)[jq];
    for (int k = 0; k < H2; ++k)
        fma4(acc, h1[g * H2 + k], ((const float4*)(Wl2 + (long)k * H2))[jq]);
    acc.x = fmaxf(acc.x, 0.f); acc.y = fmaxf(acc.y, 0.f);
    acc.z = fmaxf(acc.z, 0.f); acc.w = fmaxf(acc.w, 0.f);
    ((float4*)h2)[g * 64 + jq] = acc;
}

__global__ void k_mlp3(const float* __restrict__ h2, const float* __restrict__ Wl3,
                       const float* __restrict__ bl3, float* __restrict__ out) {
    int gw = (blockIdx.x * 256 + threadIdx.x) >> 6;
    int lane = threadIdx.x & 63;
    if (gw >= NGRAPH) return;
    float sum = 0.0f;
    for (int k = lane; k < H2; k += 64)
        sum += h2[gw * H2 + k] * Wl3[k];
    for (int off = 32; off; off >>= 1)
        sum += __shfl_down(sum, off);
    if (lane == 0) out[gw] = sum + bl3[0];
}

extern "C" void kernel_launch(void* const* d_in, const int* in_sizes, int n_in,
                              void* d_out, int out_size, void* d_ws, size_t ws_size,
                              hipStream_t stream) {
    const float* feats_node  = (const float*)d_in[0];
    const float* feats_graph = (const float*)d_in[1];
    const float* W1 = (const float*)d_in[2];
    const float* b1 = (const float*)d_in[3];
    const float* W2 = (const float*)d_in[4];
    const float* b2 = (const float*)d_in[5];
    const float* W3 = (const float*)d_in[6];
    const float* b3 = (const float*)d_in[7];
    const float* Wl1 = (const float*)d_in[8];
    const float* bl1 = (const float*)d_in[9];
    const float* Wl2 = (const float*)d_in[10];
    const float* bl2 = (const float*)d_in[11];
    const float* Wl3 = (const float*)d_in[12];
    const float* bl3 = (const float*)d_in[13];
    const int* src  = (const int*)d_in[14];
    const int* dst  = (const int*)d_in[15];
    const int* gids = (const int*)d_in[16];
    float* out = (float*)d_out;

    // workspace layout
    float* ws = (float*)d_ws;
    float* c_out     = ws;                        // 50048
    float* c_in      = c_out + 50048;             // 50048
    float* A         = c_in + 50048;              // N*H
    float* B         = A + (size_t)NNODES * H;    // N*H
    int*   row_start = (int*)(B + (size_t)NNODES * H);  // 50176
    int*   csr_src   = row_start + 50176;         // 600000
    int*   cursor    = csr_src + NEDGES;          // 50176
    int*   gstart    = cursor + 50176;            // 2048
    float* mean      = (float*)(gstart + 2048);   // G*H
    float* h1        = mean + (size_t)NGRAPH * H; // G*H2
    float* h2        = h1 + (size_t)NGRAPH * H2;  // G*H2

    // degrees
    hipMemsetAsync(c_out, 0, 2 * 50048 * sizeof(float), stream);
    k_deg<<<(NEDGES + 255) / 256, 256, 0, stream>>>(src, dst, c_out, c_in);

    // CSR build, then normalize degrees
    k_scan<<<1, 1024, 0, stream>>>(c_in, row_start);
    hipMemsetAsync(cursor, 0, 50176 * sizeof(int), stream);
    k_fill<<<(NEDGES + 255) / 256, 256, 0, stream>>>(src, dst, row_start, cursor, csr_src);
    k_cnorm<<<(NNODES + 255) / 256, 256, 0, stream>>>(c_out, c_in);
    k_gbounds<<<(NNODES + 256) / 256, 256, 0, stream>>>(gids, gstart);

    const int GEMM_GRID = (NNODES + 127) / 128;

    // layer 1
    k_gather<F0><<<NNODES / 4, 256, 0, stream>>>(feats_node, c_out, row_start, csr_src, A);
    k_gemm<F0, true><<<GEMM_GRID, 512, 0, stream>>>(A, c_in, W1, b1, B);

    // layer 2
    k_gather<H><<<NNODES / 4, 256, 0, stream>>>(B, c_out, row_start, csr_src, A);
    k_gemm<H, true><<<GEMM_GRID, 512, 0, stream>>>(A, c_in, W2, b2, B);

    // layer 3 (no relu)
    k_gather<H><<<NNODES / 4, 256, 0, stream>>>(B, c_out, row_start, csr_src, A);
    k_gemm<H, false><<<GEMM_GRID, 512, 0, stream>>>(A, c_in, W3, b3, B);

    // readout mean
    k_readout<<<NGRAPH / 2, 256, 0, stream>>>(B, gstart, mean);

    // MLP head
    k_mlp1<<<NGRAPH / 4, 256, 0, stream>>>(mean, feats_graph, Wl1, bl1, h1);
    k_mlp2<<<NGRAPH / 4, 256, 0, stream>>>(h1, Wl2, bl2, h2);
    k_mlp3<<<(NGRAPH * 64 + 255) / 256, 256, 0, stream>>>(h2, Wl3, bl3, out);
}

// Round 5
// 459.118 us; speedup vs baseline: 6.7370x; 1.1834x over previous
//
#include <hip/hip_runtime.h>

constexpr int NNODES = 50000;
constexpr int NEDGES = 600000;
constexpr int NGRAPH = 2000;
constexpr int F0     = 64;    // IN_FEATS
constexpr int H      = 128;   // HIDDEN
constexpr int H2     = 256;   // 2*HIDDEN
constexpr int NB     = 49;    // scan blocks: 49*1024 >= 50000

static __device__ __forceinline__ void fma4(float4& acc, float s, const float4& w) {
    acc.x = fmaf(s, w.x, acc.x);
    acc.y = fmaf(s, w.y, acc.y);
    acc.z = fmaf(s, w.z, acc.z);
    acc.w = fmaf(s, w.w, acc.w);
}

// ---------------- degree count ----------------
__global__ void k_deg(const int* __restrict__ src, const int* __restrict__ dst,
                      float* __restrict__ dout, float* __restrict__ din) {
    int e = blockIdx.x * 256 + threadIdx.x;
    if (e < NEDGES) {
        atomicAdd(&dout[src[e]], 1.0f);
        atomicAdd(&din[dst[e]], 1.0f);
    }
}

// ---------------- hierarchical exclusive scan of deg_in -> row_start ----------------
// phase 1: per-block scan (wave shfl + LDS wave-sum combine), block totals -> partials
__global__ __launch_bounds__(1024) void k_scan1(const float* __restrict__ degf,
                                                int* __restrict__ row_start,
                                                int* __restrict__ partials) {
    __shared__ int wsum[16];
    int idx  = blockIdx.x * 1024 + threadIdx.x;
    int lane = threadIdx.x & 63;
    int wid  = threadIdx.x >> 6;
    int v = (idx < NNODES) ? (int)degf[idx] : 0;
    int incl = v;
#pragma unroll
    for (int off = 1; off < 64; off <<= 1) {
        int t = __shfl_up(incl, off);
        if (lane >= off) incl += t;
    }
    if (lane == 63) wsum[wid] = incl;
    __syncthreads();
    if (wid == 0) {
        int w = (lane < 16) ? wsum[lane] : 0;
        int wincl = w;
#pragma unroll
        for (int off = 1; off < 16; off <<= 1) {
            int t = __shfl_up(wincl, off);
            if (lane >= off) wincl += t;
        }
        if (lane < 16) wsum[lane] = wincl - w;  // exclusive wave offset
    }
    __syncthreads();
    int excl = wsum[wid] + incl - v;            // block-local exclusive
    if (idx < NNODES) row_start[idx] = excl;
    if (threadIdx.x == 1023) partials[blockIdx.x] = excl + v;  // block total
}

// phase 2: scan the NB block totals with one wave
__global__ void k_scan2(int* __restrict__ partials) {
    int lane = threadIdx.x;
    int v = (lane < NB) ? partials[lane] : 0;
    int incl = v;
#pragma unroll
    for (int off = 1; off < 64; off <<= 1) {
        int t = __shfl_up(incl, off);
        if (lane >= off) incl += t;
    }
    if (lane < NB) partials[lane] = incl - v;   // exclusive
    if (lane == NB - 1) partials[NB] = incl;    // grand total (= NEDGES)
}

// phase 3: add block offsets; write sentinel
__global__ __launch_bounds__(1024) void k_scan3(int* __restrict__ row_start,
                                                const int* __restrict__ partials) {
    int idx = blockIdx.x * 1024 + threadIdx.x;
    if (idx < NNODES) row_start[idx] += partials[blockIdx.x];
    else if (idx == NNODES) row_start[NNODES] = partials[NB];
}

// fill CSR
__global__ void k_fill(const int* __restrict__ src, const int* __restrict__ dst,
                       const int* __restrict__ row_start, int* __restrict__ cursor,
                       int* __restrict__ csr_src) {
    int e = blockIdx.x * 256 + threadIdx.x;
    if (e < NEDGES) {
        int d = dst[e];
        int p = atomicAdd(&cursor[d], 1);
        csr_src[row_start[d] + p] = src[e];
    }
}

// deg -> rsqrt(max(deg,1))
__global__ void k_cnorm(float* __restrict__ c_out, float* __restrict__ c_in) {
    int n = blockIdx.x * 256 + threadIdx.x;
    if (n < NNODES) {
        c_out[n] = rsqrtf(fmaxf(c_out[n], 1.0f));
        c_in[n]  = rsqrtf(fmaxf(c_in[n], 1.0f));
    }
}

// graph segment boundaries from sorted graph_ids
__global__ void k_gbounds(const int* __restrict__ gids, int* __restrict__ gstart) {
    int n = blockIdx.x * 256 + threadIdx.x;
    if (n > NNODES) return;
    if (n == 0) {
        int g0 = gids[0];
        for (int g = 0; g <= g0; ++g) gstart[g] = 0;
    } else if (n == NNODES) {
        int gl = gids[NNODES - 1];
        for (int g = gl + 1; g <= NGRAPH; ++g) gstart[g] = NNODES;
    } else {
        int a = gids[n - 1], b = gids[n];
        for (int g = a + 1; g <= b; ++g) gstart[g] = n;
    }
}

// ---------------- gather aggregation ----------------
template <int F>
__global__ __launch_bounds__(256) void k_gather(const float* __restrict__ x,
                                                const float* __restrict__ c_out,
                                                const int* __restrict__ row_start,
                                                const int* __restrict__ csr_src,
                                                float* __restrict__ agg) {
    int wid  = (blockIdx.x * 256 + threadIdx.x) >> 6;
    int lane = threadIdx.x & 63;
    if (wid >= NNODES) return;
    int beg = row_start[wid], end = row_start[wid + 1];
    if (F == 128) {
        const float2* x2 = (const float2*)x;
        float2 acc = make_float2(0.f, 0.f);
#pragma unroll 4
        for (int i = beg; i < end; ++i) {
            int s = csr_src[i];
            float co = c_out[s];
            float2 v = x2[(long)s * 64 + lane];
            acc.x += v.x * co;
            acc.y += v.y * co;
        }
        ((float2*)agg)[(long)wid * 64 + lane] = acc;
    } else {
        float acc = 0.f;
#pragma unroll 4
        for (int i = beg; i < end; ++i) {
            int s = csr_src[i];
            acc += x[(long)s * F + lane] * c_out[s];
        }
        agg[(long)wid * F + lane] = acc;
    }
}

// ---------------- register-blocked fused GEMM ----------------
template <int K, bool RELU>
__global__ __launch_bounds__(512) void k_gemm(const float* __restrict__ A,
                                              const float* __restrict__ c_in,
                                              const float* __restrict__ W,
                                              const float* __restrict__ b,
                                              float* __restrict__ out) {
    __shared__ float sW[K * H];
    for (int i = threadIdx.x; i < K * (H / 4); i += 512)
        ((float4*)sW)[i] = ((const float4*)W)[i];
    __syncthreads();

    const int c = threadIdx.x & 31;
    const int r = threadIdx.x >> 5;
    const long base = (long)blockIdx.x * 128 + r * 8;

    float4 acc[8];
#pragma unroll
    for (int i = 0; i < 8; ++i) acc[i] = make_float4(0.f, 0.f, 0.f, 0.f);

    const float4* Ap = (const float4*)A + base * (K / 4);

    for (int k4 = 0; k4 < K / 4; ++k4) {
        const float4 w0 = *(const float4*)&sW[(4 * k4 + 0) * H + 4 * c];
        const float4 w1 = *(const float4*)&sW[(4 * k4 + 1) * H + 4 * c];
        const float4 w2 = *(const float4*)&sW[(4 * k4 + 2) * H + 4 * c];
        const float4 w3 = *(const float4*)&sW[(4 * k4 + 3) * H + 4 * c];
#pragma unroll
        for (int i = 0; i < 8; ++i) {
            float4 a = Ap[(long)i * (K / 4) + k4];
            fma4(acc[i], a.x, w0);
            fma4(acc[i], a.y, w1);
            fma4(acc[i], a.z, w2);
            fma4(acc[i], a.w, w3);
        }
    }

    const float4 bv = ((const float4*)b)[c];
#pragma unroll
    for (int i = 0; i < 8; ++i) {
        long n = base + i;
        if (n < NNODES) {
            float ci = c_in[n];
            float4 res;
            res.x = fmaf(acc[i].x, ci, bv.x);
            res.y = fmaf(acc[i].y, ci, bv.y);
            res.z = fmaf(acc[i].z, ci, bv.z);
            res.w = fmaf(acc[i].w, ci, bv.w);
            if (RELU) {
                res.x = fmaxf(res.x, 0.f);
                res.y = fmaxf(res.y, 0.f);
                res.z = fmaxf(res.z, 0.f);
                res.w = fmaxf(res.w, 0.f);
            }
            ((float4*)out)[n * (H / 4) + c] = res;
        }
    }
}

// ---------------- segment-mean readout (2 graphs per block) ----------------
__global__ void k_readout(const float* __restrict__ y, const int* __restrict__ gstart,
                          float* __restrict__ mean) {
    int g = blockIdx.x * 2 + (threadIdx.x >> 7);
    int j = threadIdx.x & 127;
    if (g >= NGRAPH) return;
    int beg = gstart[g], end = gstart[g + 1];
    float acc = 0.f;
    for (int n = beg; n < end; ++n) acc += y[(long)n * H + j];
    mean[g * H + j] = acc / fmaxf((float)(end - beg), 1.0f);
}

// ---------------- MLP head ----------------
__global__ void k_mlp1(const float* __restrict__ mean, const float* __restrict__ fg,
                       const float* __restrict__ Wl1, const float* __restrict__ bl1,
                       float* __restrict__ h1) {
    int g  = blockIdx.x * 4 + (threadIdx.x >> 6);
    int jq = threadIdx.x & 63;
    if (g >= NGRAPH) return;
    float4 acc = ((const float4*)bl1)[jq];
    for (int k = 0; k < H; ++k)
        fma4(acc, mean[g * H + k], ((const float4*)(Wl1 + (long)k * H2))[jq]);
    for (int k = 0; k < 3; ++k)
        fma4(acc, fg[g * 3 + k], ((const float4*)(Wl1 + (long)(H + k) * H2))[jq]);
    acc.x = fmaxf(acc.x, 0.f); acc.y = fmaxf(acc.y, 0.f);
    acc.z = fmaxf(acc.z, 0.f); acc.w = fmaxf(acc.w, 0.f);
    ((float4*)h1)[g * 64 + jq] = acc;
}

__global__ void k_mlp2(const float* __restrict__ h1, const float* __restrict__ Wl2,
                       const float* __restrict__ bl2, float* __restrict__ h2) {
    int g  = blockIdx.x * 4 + (threadIdx.x >> 6);
    int jq = threadIdx.x & 63;
    if (g >= NGRAPH) return;
    float4 acc = ((const float4*)bl2)[jq];
    for (int k = 0; k < H2; ++k)
        fma4(acc, h1[g * H2 + k], ((const float4*)(Wl2 + (long)k * H2))[jq]);
    acc.x = fmaxf(acc.x, 0.f); acc.y = fmaxf(acc.y, 0.f);
    acc.z = fmaxf(acc.z, 0.f); acc.w = fmaxf(acc.w, 0.f);
    ((float4*)h2)[g * 64 + jq] = acc;
}

__global__ void k_mlp3(const float* __restrict__ h2, const float* __restrict__ Wl3,
                       const float* __restrict__ bl3, float* __restrict__ out) {
    int gw = (blockIdx.x * 256 + threadIdx.x) >> 6;
    int lane = threadIdx.x & 63;
    if (gw >= NGRAPH) return;
    float sum = 0.0f;
    for (int k = lane; k < H2; k += 64)
        sum += h2[gw * H2 + k] * Wl3[k];
    for (int off = 32; off; off >>= 1)
        sum += __shfl_down(sum, off);
    if (lane == 0) out[gw] = sum + bl3[0];
}

extern "C" void kernel_launch(void* const* d_in, const int* in_sizes, int n_in,
                              void* d_out, int out_size, void* d_ws, size_t ws_size,
                              hipStream_t stream) {
    const float* feats_node  = (const float*)d_in[0];
    const float* feats_graph = (const float*)d_in[1];
    const float* W1 = (const float*)d_in[2];
    const float* b1 = (const float*)d_in[3];
    const float* W2 = (const float*)d_in[4];
    const float* b2 = (const float*)d_in[5];
    const float* W3 = (const float*)d_in[6];
    const float* b3 = (const float*)d_in[7];
    const float* Wl1 = (const float*)d_in[8];
    const float* bl1 = (const float*)d_in[9];
    const float* Wl2 = (const float*)d_in[10];
    const float* bl2 = (const float*)d_in[11];
    const float* Wl3 = (const float*)d_in[12];
    const float* bl3 = (const float*)d_in[13];
    const int* src  = (const int*)d_in[14];
    const int* dst  = (const int*)d_in[15];
    const int* gids = (const int*)d_in[16];
    float* out = (float*)d_out;

    // workspace layout
    float* ws = (float*)d_ws;
    float* c_out     = ws;                        // 50048
    float* c_in      = c_out + 50048;             // 50048
    float* A         = c_in + 50048;              // N*H
    float* B         = A + (size_t)NNODES * H;    // N*H
    int*   row_start = (int*)(B + (size_t)NNODES * H);  // 50176
    int*   csr_src   = row_start + 50176;         // 600000
    int*   cursor    = csr_src + NEDGES;          // 50176
    int*   gstart    = cursor + 50176;            // 2048
    int*   partials  = gstart + 2048;             // 64
    float* mean      = (float*)(partials + 64);   // G*H
    float* h1        = mean + (size_t)NGRAPH * H; // G*H2
    float* h2        = h1 + (size_t)NGRAPH * H2;  // G*H2

    // degrees
    hipMemsetAsync(c_out, 0, 2 * 50048 * sizeof(float), stream);
    k_deg<<<(NEDGES + 255) / 256, 256, 0, stream>>>(src, dst, c_out, c_in);

    // CSR build (hierarchical scan), then normalize degrees
    k_scan1<<<NB, 1024, 0, stream>>>(c_in, row_start, partials);
    k_scan2<<<1, 64, 0, stream>>>(partials);
    k_scan3<<<NB, 1024, 0, stream>>>(row_start, partials);
    hipMemsetAsync(cursor, 0, 50176 * sizeof(int), stream);
    k_fill<<<(NEDGES + 255) / 256, 256, 0, stream>>>(src, dst, row_start, cursor, csr_src);
    k_cnorm<<<(NNODES + 255) / 256, 256, 0, stream>>>(c_out, c_in);
    k_gbounds<<<(NNODES + 256) / 256, 256, 0, stream>>>(gids, gstart);

    const int GEMM_GRID = (NNODES + 127) / 128;

    // layer 1
    k_gather<F0><<<NNODES / 4, 256, 0, stream>>>(feats_node, c_out, row_start, csr_src, A);
    k_gemm<F0, true><<<GEMM_GRID, 512, 0, stream>>>(A, c_in, W1, b1, B);

    // layer 2
    k_gather<H><<<NNODES / 4, 256, 0, stream>>>(B, c_out, row_start, csr_src, A);
    k_gemm<H, true><<<GEMM_GRID, 512, 0, stream>>>(A, c_in, W2, b2, B);

    // layer 3 (no relu)
    k_gather<H><<<NNODES / 4, 256, 0, stream>>>(B, c_out, row_start, csr_src, A);
    k_gemm<H, false><<<GEMM_GRID, 512, 0, stream>>>(A, c_in, W3, b3, B);

    // readout mean
    k_readout<<<NGRAPH / 2, 256, 0, stream>>>(B, gstart, mean);

    // MLP head
    k_mlp1<<<NGRAPH / 4, 256, 0, stream>>>(mean, feats_graph, Wl1, bl1, h1);
    k_mlp2<<<NGRAPH / 4, 256, 0, stream>>>(h1, Wl2, bl2, h2);
    k_mlp3<<<(NGRAPH * 64 + 255) / 256, 256, 0, stream>>>(h2, Wl3, bl3, out);
}

// Round 6
// 458.858 us; speedup vs baseline: 6.7408x; 1.0006x over previous
//
#include <hip/hip_runtime.h>

constexpr int NNODES = 50000;
constexpr int NEDGES = 600000;
constexpr int NGRAPH = 2000;
constexpr int F0     = 64;    // IN_FEATS
constexpr int H      = 128;   // HIDDEN
constexpr int H2     = 256;   // 2*HIDDEN
constexpr int NB     = 49;    // scan blocks: 49*1024 >= 50000

static __device__ __forceinline__ void fma4(float4& acc, float s, const float4& w) {
    acc.x = fmaf(s, w.x, acc.x);
    acc.y = fmaf(s, w.y, acc.y);
    acc.z = fmaf(s, w.z, acc.z);
    acc.w = fmaf(s, w.w, acc.w);
}

// ---------------- degree count: 4 edges/thread, int atomics ----------------
__global__ void k_deg(const int* __restrict__ src, const int* __restrict__ dst,
                      int* __restrict__ dout, int* __restrict__ din) {
    int t = blockIdx.x * 256 + threadIdx.x;
    if (t * 4 >= NEDGES) return;
    int4 s4 = ((const int4*)src)[t];
    int4 d4 = ((const int4*)dst)[t];
    atomicAdd(&dout[s4.x], 1);
    atomicAdd(&dout[s4.y], 1);
    atomicAdd(&dout[s4.z], 1);
    atomicAdd(&dout[s4.w], 1);
    atomicAdd(&din[d4.x], 1);
    atomicAdd(&din[d4.y], 1);
    atomicAdd(&din[d4.z], 1);
    atomicAdd(&din[d4.w], 1);
}

// ---------------- hierarchical exclusive scan of deg_in -> row_start ----------------
// phase 1: per-block scan; also writes c_in = rsqrt(max(deg_in,1))
__global__ __launch_bounds__(1024) void k_scan1(const int* __restrict__ deg,
                                                int* __restrict__ row_start,
                                                int* __restrict__ partials,
                                                float* __restrict__ c_in) {
    __shared__ int wsum[16];
    int idx  = blockIdx.x * 1024 + threadIdx.x;
    int lane = threadIdx.x & 63;
    int wid  = threadIdx.x >> 6;
    int v = (idx < NNODES) ? deg[idx] : 0;
    if (idx < NNODES) c_in[idx] = rsqrtf(fmaxf((float)v, 1.0f));
    int incl = v;
#pragma unroll
    for (int off = 1; off < 64; off <<= 1) {
        int t = __shfl_up(incl, off);
        if (lane >= off) incl += t;
    }
    if (lane == 63) wsum[wid] = incl;
    __syncthreads();
    if (wid == 0) {
        int w = (lane < 16) ? wsum[lane] : 0;
        int wincl = w;
#pragma unroll
        for (int off = 1; off < 16; off <<= 1) {
            int t = __shfl_up(wincl, off);
            if (lane >= off) wincl += t;
        }
        if (lane < 16) wsum[lane] = wincl - w;
    }
    __syncthreads();
    int excl = wsum[wid] + incl - v;
    if (idx < NNODES) row_start[idx] = excl;
    if (threadIdx.x == 1023) partials[blockIdx.x] = excl + v;
}

// phase 2: scan the NB block totals with one wave
__global__ void k_scan2(int* __restrict__ partials) {
    int lane = threadIdx.x;
    int v = (lane < NB) ? partials[lane] : 0;
    int incl = v;
#pragma unroll
    for (int off = 1; off < 64; off <<= 1) {
        int t = __shfl_up(incl, off);
        if (lane >= off) incl += t;
    }
    if (lane < NB) partials[lane] = incl - v;
    if (lane == NB - 1) partials[NB] = incl;
}

// phase 3: add block offsets; sentinel; also c_out = rsqrt(max(deg_out,1))
__global__ __launch_bounds__(1024) void k_scan3(int* __restrict__ row_start,
                                                const int* __restrict__ partials,
                                                const int* __restrict__ dout,
                                                float* __restrict__ c_out) {
    int idx = blockIdx.x * 1024 + threadIdx.x;
    if (idx < NNODES) {
        row_start[idx] += partials[blockIdx.x];
        c_out[idx] = rsqrtf(fmaxf((float)dout[idx], 1.0f));
    } else if (idx == NNODES) {
        row_start[NNODES] = partials[NB];
    }
}

// fill CSR: 4 edges/thread
__global__ void k_fill(const int* __restrict__ src, const int* __restrict__ dst,
                       const int* __restrict__ row_start, int* __restrict__ cursor,
                       int* __restrict__ csr_src) {
    int t = blockIdx.x * 256 + threadIdx.x;
    if (t * 4 >= NEDGES) return;
    int4 s4 = ((const int4*)src)[t];
    int4 d4 = ((const int4*)dst)[t];
    int p;
    p = atomicAdd(&cursor[d4.x], 1); csr_src[row_start[d4.x] + p] = s4.x;
    p = atomicAdd(&cursor[d4.y], 1); csr_src[row_start[d4.y] + p] = s4.y;
    p = atomicAdd(&cursor[d4.z], 1); csr_src[row_start[d4.z] + p] = s4.z;
    p = atomicAdd(&cursor[d4.w], 1); csr_src[row_start[d4.w] + p] = s4.w;
}

// graph segment boundaries from sorted graph_ids
__global__ void k_gbounds(const int* __restrict__ gids, int* __restrict__ gstart) {
    int n = blockIdx.x * 256 + threadIdx.x;
    if (n > NNODES) return;
    if (n == 0) {
        int g0 = gids[0];
        for (int g = 0; g <= g0; ++g) gstart[g] = 0;
    } else if (n == NNODES) {
        int gl = gids[NNODES - 1];
        for (int g = gl + 1; g <= NGRAPH; ++g) gstart[g] = NNODES;
    } else {
        int a = gids[n - 1], b = gids[n];
        for (int g = a + 1; g <= b; ++g) gstart[g] = n;
    }
}

// ---------------- gather aggregation: 2 edges in parallel per wave ----------------
// half-wave h handles edges beg+h, beg+h+2, ...; lanes q split the feature row.
template <int F>
__global__ __launch_bounds__(256) void k_gather(const float* __restrict__ x,
                                                const float* __restrict__ c_out,
                                                const int* __restrict__ row_start,
                                                const int* __restrict__ csr_src,
                                                float* __restrict__ agg) {
    int wid  = (blockIdx.x * 256 + threadIdx.x) >> 6;
    int lane = threadIdx.x & 63;
    int h = lane >> 5, q = lane & 31;
    if (wid >= NNODES) return;
    int beg = row_start[wid], end = row_start[wid + 1];
    if (F == 128) {
        const float4* x4 = (const float4*)x;
        float4 acc = make_float4(0.f, 0.f, 0.f, 0.f);
        for (int i = beg + h; i < end; i += 2) {
            int s = csr_src[i];
            float co = c_out[s];
            float4 v = x4[(long)s * 32 + q];
            acc.x += v.x * co;
            acc.y += v.y * co;
            acc.z += v.z * co;
            acc.w += v.w * co;
        }
        acc.x += __shfl_xor(acc.x, 32);
        acc.y += __shfl_xor(acc.y, 32);
        acc.z += __shfl_xor(acc.z, 32);
        acc.w += __shfl_xor(acc.w, 32);
        if (h == 0) ((float4*)agg)[(long)wid * 32 + q] = acc;
    } else {
        const float2* x2 = (const float2*)x;
        float2 acc = make_float2(0.f, 0.f);
        for (int i = beg + h; i < end; i += 2) {
            int s = csr_src[i];
            float co = c_out[s];
            float2 v = x2[(long)s * 32 + q];
            acc.x += v.x * co;
            acc.y += v.y * co;
        }
        acc.x += __shfl_xor(acc.x, 32);
        acc.y += __shfl_xor(acc.y, 32);
        if (h == 0) ((float2*)agg)[(long)wid * 32 + q] = acc;
    }
}

// ---------------- register-blocked fused GEMM ----------------
template <int K, bool RELU>
__global__ __launch_bounds__(512) void k_gemm(const float* __restrict__ A,
                                              const float* __restrict__ c_in,
                                              const float* __restrict__ W,
                                              const float* __restrict__ b,
                                              float* __restrict__ out) {
    __shared__ float sW[K * H];
    for (int i = threadIdx.x; i < K * (H / 4); i += 512)
        ((float4*)sW)[i] = ((const float4*)W)[i];
    __syncthreads();

    const int c = threadIdx.x & 31;
    const int r = threadIdx.x >> 5;
    const long base = (long)blockIdx.x * 128 + r * 8;

    float4 acc[8];
#pragma unroll
    for (int i = 0; i < 8; ++i) acc[i] = make_float4(0.f, 0.f, 0.f, 0.f);

    const float4* Ap = (const float4*)A + base * (K / 4);

    for (int k4 = 0; k4 < K / 4; ++k4) {
        const float4 w0 = *(const float4*)&sW[(4 * k4 + 0) * H + 4 * c];
        const float4 w1 = *(const float4*)&sW[(4 * k4 + 1) * H + 4 * c];
        const float4 w2 = *(const float4*)&sW[(4 * k4 + 2) * H + 4 * c];
        const float4 w3 = *(const float4*)&sW[(4 * k4 + 3) * H + 4 * c];
#pragma unroll
        for (int i = 0; i < 8; ++i) {
            float4 a = Ap[(long)i * (K / 4) + k4];
            fma4(acc[i], a.x, w0);
            fma4(acc[i], a.y, w1);
            fma4(acc[i], a.z, w2);
            fma4(acc[i], a.w, w3);
        }
    }

    const float4 bv = ((const float4*)b)[c];
#pragma unroll
    for (int i = 0; i < 8; ++i) {
        long n = base + i;
        if (n < NNODES) {
            float ci = c_in[n];
            float4 res;
            res.x = fmaf(acc[i].x, ci, bv.x);
            res.y = fmaf(acc[i].y, ci, bv.y);
            res.z = fmaf(acc[i].z, ci, bv.z);
            res.w = fmaf(acc[i].w, ci, bv.w);
            if (RELU) {
                res.x = fmaxf(res.x, 0.f);
                res.y = fmaxf(res.y, 0.f);
                res.z = fmaxf(res.z, 0.f);
                res.w = fmaxf(res.w, 0.f);
            }
            ((float4*)out)[n * (H / 4) + c] = res;
        }
    }
}

// ---------------- segment-mean readout (2 graphs per block) ----------------
__global__ void k_readout(const float* __restrict__ y, const int* __restrict__ gstart,
                          float* __restrict__ mean) {
    int g = blockIdx.x * 2 + (threadIdx.x >> 7);
    int j = threadIdx.x & 127;
    if (g >= NGRAPH) return;
    int beg = gstart[g], end = gstart[g + 1];
    float acc = 0.f;
    for (int n = beg; n < end; ++n) acc += y[(long)n * H + j];
    mean[g * H + j] = acc / fmaxf((float)(end - beg), 1.0f);
}

// ---------------- MLP head ----------------
__global__ void k_mlp1(const float* __restrict__ mean, const float* __restrict__ fg,
                       const float* __restrict__ Wl1, const float* __restrict__ bl1,
                       float* __restrict__ h1) {
    int g  = blockIdx.x * 4 + (threadIdx.x >> 6);
    int jq = threadIdx.x & 63;
    if (g >= NGRAPH) return;
    float4 acc = ((const float4*)bl1)[jq];
    for (int k = 0; k < H; ++k)
        fma4(acc, mean[g * H + k], ((const float4*)(Wl1 + (long)k * H2))[jq]);
    for (int k = 0; k < 3; ++k)
        fma4(acc, fg[g * 3 + k], ((const float4*)(Wl1 + (long)(H + k) * H2))[jq]);
    acc.x = fmaxf(acc.x, 0.f); acc.y = fmaxf(acc.y, 0.f);
    acc.z = fmaxf(acc.z, 0.f); acc.w = fmaxf(acc.w, 0.f);
    ((float4*)h1)[g * 64 + jq] = acc;
}

__global__ void k_mlp2(const float* __restrict__ h1, const float* __restrict__ Wl2,
                       const float* __restrict__ bl2, float* __restrict__ h2) {
    int g  = blockIdx.x * 4 + (threadIdx.x >> 6);
    int jq = threadIdx.x & 63;
    if (g >= NGRAPH) return;
    float4 acc = ((const float4*)bl2)[jq];
    for (int k = 0; k < H2; ++k)
        fma4(acc, h1[g * H2 + k], ((const float4*)(Wl2 + (long)k * H2))[jq]);
    acc.x = fmaxf(acc.x, 0.f); acc.y = fmaxf(acc.y, 0.f);
    acc.z = fmaxf(acc.z, 0.f); acc.w = fmaxf(acc.w, 0.f);
    ((float4*)h2)[g * 64 + jq] = acc;
}

__global__ void k_mlp3(const float* __restrict__ h2, const float* __restrict__ Wl3,
                       const float* __restrict__ bl3, float* __restrict__ out) {
    int gw = (blockIdx.x * 256 + threadIdx.x) >> 6;
    int lane = threadIdx.x & 63;
    if (gw >= NGRAPH) return;
    float sum = 0.0f;
    for (int k = lane; k < H2; k += 64)
        sum += h2[gw * H2 + k] * Wl3[k];
    for (int off = 32; off; off >>= 1)
        sum += __shfl_down(sum, off);
    if (lane == 0) out[gw] = sum + bl3[0];
}

extern "C" void kernel_launch(void* const* d_in, const int* in_sizes, int n_in,
                              void* d_out, int out_size, void* d_ws, size_t ws_size,
                              hipStream_t stream) {
    const float* feats_node  = (const float*)d_in[0];
    const float* feats_graph = (const float*)d_in[1];
    const float* W1 = (const float*)d_in[2];
    const float* b1 = (const float*)d_in[3];
    const float* W2 = (const float*)d_in[4];
    const float* b2 = (const float*)d_in[5];
    const float* W3 = (const float*)d_in[6];
    const float* b3 = (const float*)d_in[7];
    const float* Wl1 = (const float*)d_in[8];
    const float* bl1 = (const float*)d_in[9];
    const float* Wl2 = (const float*)d_in[10];
    const float* bl2 = (const float*)d_in[11];
    const float* Wl3 = (const float*)d_in[12];
    const float* bl3 = (const float*)d_in[13];
    const int* src  = (const int*)d_in[14];
    const int* dst  = (const int*)d_in[15];
    const int* gids = (const int*)d_in[16];
    float* out = (float*)d_out;

    // workspace layout (4B units)
    float* ws = (float*)d_ws;
    float* c_out     = ws;                        // 50048
    float* c_in      = c_out + 50048;             // 50048
    float* A         = c_in + 50048;              // N*H
    float* B         = A + (size_t)NNODES * H;    // N*H
    int*   row_start = (int*)(B + (size_t)NNODES * H);  // 50176
    int*   csr_src   = row_start + 50176;         // 600000
    int*   cursor    = csr_src + NEDGES;          // 50176
    int*   gstart    = cursor + 50176;            // 2048
    int*   partials  = gstart + 2048;             // 64
    int*   dout      = partials + 64;             // 50048
    int*   din       = dout + 50048;              // 50048
    float* mean      = (float*)(din + 50048);     // G*H
    float* h1        = mean + (size_t)NGRAPH * H; // G*H2
    float* h2        = h1 + (size_t)NGRAPH * H2;  // G*H2

    // degrees (int)
    hipMemsetAsync(dout, 0, 2 * 50048 * sizeof(int), stream);
    k_deg<<<(NEDGES / 4 + 255) / 256, 256, 0, stream>>>(src, dst, dout, din);

    // CSR build (hierarchical scan) + fused cnorm
    k_scan1<<<NB, 1024, 0, stream>>>(din, row_start, partials, c_in);
    k_scan2<<<1, 64, 0, stream>>>(partials);
    k_scan3<<<NB, 1024, 0, stream>>>(row_start, partials, dout, c_out);
    hipMemsetAsync(cursor, 0, 50176 * sizeof(int), stream);
    k_fill<<<(NEDGES / 4 + 255) / 256, 256, 0, stream>>>(src, dst, row_start, cursor, csr_src);
    k_gbounds<<<(NNODES + 256) / 256, 256, 0, stream>>>(gids, gstart);

    const int GEMM_GRID = (NNODES + 127) / 128;

    // layer 1
    k_gather<F0><<<NNODES / 4, 256, 0, stream>>>(feats_node, c_out, row_start, csr_src, A);
    k_gemm<F0, true><<<GEMM_GRID, 512, 0, stream>>>(A, c_in, W1, b1, B);

    // layer 2
    k_gather<H><<<NNODES / 4, 256, 0, stream>>>(B, c_out, row_start, csr_src, A);
    k_gemm<H, true><<<GEMM_GRID, 512, 0, stream>>>(A, c_in, W2, b2, B);

    // layer 3 (no relu)
    k_gather<H><<<NNODES / 4, 256, 0, stream>>>(B, c_out, row_start, csr_src, A);
    k_gemm<H, false><<<GEMM_GRID, 512, 0, stream>>>(A, c_in, W3, b3, B);

    // readout mean
    k_readout<<<NGRAPH / 2, 256, 0, stream>>>(B, gstart, mean);

    // MLP head
    k_mlp1<<<NGRAPH / 4, 256, 0, stream>>>(mean, feats_graph, Wl1, bl1, h1);
    k_mlp2<<<NGRAPH / 4, 256, 0, stream>>>(h1, Wl2, bl2, h2);
    k_mlp3<<<(NGRAPH * 64 + 255) / 256, 256, 0, stream>>>(h2, Wl3, bl3, out);
}

// Round 7
// 428.629 us; speedup vs baseline: 7.2162x; 1.0705x over previous
//
#include <hip/hip_runtime.h>

constexpr int NNODES = 50000;
constexpr int NEDGES = 600000;
constexpr int NGRAPH = 2000;
constexpr int F0     = 64;    // IN_FEATS
constexpr int H      = 128;   // HIDDEN
constexpr int H2     = 256;   // 2*HIDDEN
constexpr int NB     = 49;    // scan blocks: 49*1024 >= 50000

static __device__ __forceinline__ void fma4(float4& acc, float s, const float4& w) {
    acc.x = fmaf(s, w.x, acc.x);
    acc.y = fmaf(s, w.y, acc.y);
    acc.z = fmaf(s, w.z, acc.z);
    acc.w = fmaf(s, w.w, acc.w);
}

// ---------------- degree count: 4 edges/thread, int atomics ----------------
__global__ void k_deg(const int* __restrict__ src, const int* __restrict__ dst,
                      int* __restrict__ dout, int* __restrict__ din) {
    int t = blockIdx.x * 256 + threadIdx.x;
    if (t * 4 >= NEDGES) return;
    int4 s4 = ((const int4*)src)[t];
    int4 d4 = ((const int4*)dst)[t];
    atomicAdd(&dout[s4.x], 1);
    atomicAdd(&dout[s4.y], 1);
    atomicAdd(&dout[s4.z], 1);
    atomicAdd(&dout[s4.w], 1);
    atomicAdd(&din[d4.x], 1);
    atomicAdd(&din[d4.y], 1);
    atomicAdd(&din[d4.z], 1);
    atomicAdd(&din[d4.w], 1);
}

// ---------------- hierarchical exclusive scan of deg_in -> row_start ----------------
__global__ __launch_bounds__(1024) void k_scan1(const int* __restrict__ deg,
                                                int* __restrict__ row_start,
                                                int* __restrict__ partials,
                                                float* __restrict__ c_in) {
    __shared__ int wsum[16];
    int idx  = blockIdx.x * 1024 + threadIdx.x;
    int lane = threadIdx.x & 63;
    int wid  = threadIdx.x >> 6;
    int v = (idx < NNODES) ? deg[idx] : 0;
    if (idx < NNODES) c_in[idx] = rsqrtf(fmaxf((float)v, 1.0f));
    int incl = v;
#pragma unroll
    for (int off = 1; off < 64; off <<= 1) {
        int t = __shfl_up(incl, off);
        if (lane >= off) incl += t;
    }
    if (lane == 63) wsum[wid] = incl;
    __syncthreads();
    if (wid == 0) {
        int w = (lane < 16) ? wsum[lane] : 0;
        int wincl = w;
#pragma unroll
        for (int off = 1; off < 16; off <<= 1) {
            int t = __shfl_up(wincl, off);
            if (lane >= off) wincl += t;
        }
        if (lane < 16) wsum[lane] = wincl - w;
    }
    __syncthreads();
    int excl = wsum[wid] + incl - v;
    if (idx < NNODES) row_start[idx] = excl;
    if (threadIdx.x == 1023) partials[blockIdx.x] = excl + v;
}

__global__ void k_scan2(int* __restrict__ partials) {
    int lane = threadIdx.x;
    int v = (lane < NB) ? partials[lane] : 0;
    int incl = v;
#pragma unroll
    for (int off = 1; off < 64; off <<= 1) {
        int t = __shfl_up(incl, off);
        if (lane >= off) incl += t;
    }
    if (lane < NB) partials[lane] = incl - v;
    if (lane == NB - 1) partials[NB] = incl;
}

// phase 3: add block offsets; sentinel; c_out = rsqrt(max(deg_out,1)); zero cursor
__global__ __launch_bounds__(1024) void k_scan3(int* __restrict__ row_start,
                                                const int* __restrict__ partials,
                                                const int* __restrict__ dout,
                                                float* __restrict__ c_out,
                                                int* __restrict__ cursor) {
    int idx = blockIdx.x * 1024 + threadIdx.x;
    if (idx < NNODES) {
        row_start[idx] += partials[blockIdx.x];
        c_out[idx] = rsqrtf(fmaxf((float)dout[idx], 1.0f));
        cursor[idx] = 0;
    } else if (idx == NNODES) {
        row_start[NNODES] = partials[NB];
    }
}

// fill CSR: 4 edges/thread
__global__ void k_fill(const int* __restrict__ src, const int* __restrict__ dst,
                       const int* __restrict__ row_start, int* __restrict__ cursor,
                       int* __restrict__ csr_src) {
    int t = blockIdx.x * 256 + threadIdx.x;
    if (t * 4 >= NEDGES) return;
    int4 s4 = ((const int4*)src)[t];
    int4 d4 = ((const int4*)dst)[t];
    int p;
    p = atomicAdd(&cursor[d4.x], 1); csr_src[row_start[d4.x] + p] = s4.x;
    p = atomicAdd(&cursor[d4.y], 1); csr_src[row_start[d4.y] + p] = s4.y;
    p = atomicAdd(&cursor[d4.z], 1); csr_src[row_start[d4.z] + p] = s4.z;
    p = atomicAdd(&cursor[d4.w], 1); csr_src[row_start[d4.w] + p] = s4.w;
}

// graph segment boundaries from sorted graph_ids
__global__ void k_gbounds(const int* __restrict__ gids, int* __restrict__ gstart) {
    int n = blockIdx.x * 256 + threadIdx.x;
    if (n > NNODES) return;
    if (n == 0) {
        int g0 = gids[0];
        for (int g = 0; g <= g0; ++g) gstart[g] = 0;
    } else if (n == NNODES) {
        int gl = gids[NNODES - 1];
        for (int g = gl + 1; g <= NGRAPH; ++g) gstart[g] = NNODES;
    } else {
        int a = gids[n - 1], b = gids[n];
        for (int g = a + 1; g <= b; ++g) gstart[g] = n;
    }
}

// ---------------- gather aggregation (R5 proven form): 1 wave/node ----------------
template <int F>
static __device__ __forceinline__ void gather_body(const float* __restrict__ x,
                                                   const float* __restrict__ c_out,
                                                   const int* __restrict__ row_start,
                                                   const int* __restrict__ csr_src,
                                                   float* __restrict__ agg) {
    int wid  = (blockIdx.x * 256 + threadIdx.x) >> 6;
    int lane = threadIdx.x & 63;
    if (wid >= NNODES) return;
    int beg = row_start[wid], end = row_start[wid + 1];
    if (F == 128) {
        const float2* x2 = (const float2*)x;
        float2 acc = make_float2(0.f, 0.f);
#pragma unroll 4
        for (int i = beg; i < end; ++i) {
            int s = csr_src[i];
            float co = c_out[s];
            float2 v = x2[(long)s * 64 + lane];
            acc.x += v.x * co;
            acc.y += v.y * co;
        }
        ((float2*)agg)[(long)wid * 64 + lane] = acc;
    } else {
        float acc = 0.f;
#pragma unroll 4
        for (int i = beg; i < end; ++i) {
            int s = csr_src[i];
            acc += x[(long)s * F + lane] * c_out[s];
        }
        agg[(long)wid * F + lane] = acc;
    }
}

__global__ __launch_bounds__(256) void k_gather1(const float* __restrict__ x,
                                                 const float* __restrict__ c_out,
                                                 const int* __restrict__ row_start,
                                                 const int* __restrict__ csr_src,
                                                 float* __restrict__ agg) {
    gather_body<F0>(x, c_out, row_start, csr_src, agg);
}
__global__ __launch_bounds__(256) void k_gather2(const float* __restrict__ x,
                                                 const float* __restrict__ c_out,
                                                 const int* __restrict__ row_start,
                                                 const int* __restrict__ csr_src,
                                                 float* __restrict__ agg) {
    gather_body<H>(x, c_out, row_start, csr_src, agg);
}
__global__ __launch_bounds__(256) void k_gather3(const float* __restrict__ x,
                                                 const float* __restrict__ c_out,
                                                 const int* __restrict__ row_start,
                                                 const int* __restrict__ csr_src,
                                                 float* __restrict__ agg) {
    gather_body<H>(x, c_out, row_start, csr_src, agg);
}

// ---------------- register-blocked fused GEMM ----------------
template <int K, bool RELU>
static __device__ __forceinline__ void gemm_body(const float* __restrict__ A,
                                                 const float* __restrict__ c_in,
                                                 const float* __restrict__ W,
                                                 const float* __restrict__ b,
                                                 float* __restrict__ out) {
    __shared__ float sW[K * H];
    for (int i = threadIdx.x; i < K * (H / 4); i += 512)
        ((float4*)sW)[i] = ((const float4*)W)[i];
    __syncthreads();

    const int c = threadIdx.x & 31;
    const int r = threadIdx.x >> 5;
    const long base = (long)blockIdx.x * 128 + r * 8;

    float4 acc[8];
#pragma unroll
    for (int i = 0; i < 8; ++i) acc[i] = make_float4(0.f, 0.f, 0.f, 0.f);

    const float4* Ap = (const float4*)A + base * (K / 4);

    for (int k4 = 0; k4 < K / 4; ++k4) {
        const float4 w0 = *(const float4*)&sW[(4 * k4 + 0) * H + 4 * c];
        const float4 w1 = *(const float4*)&sW[(4 * k4 + 1) * H + 4 * c];
        const float4 w2 = *(const float4*)&sW[(4 * k4 + 2) * H + 4 * c];
        const float4 w3 = *(const float4*)&sW[(4 * k4 + 3) * H + 4 * c];
#pragma unroll
        for (int i = 0; i < 8; ++i) {
            float4 a = Ap[(long)i * (K / 4) + k4];
            fma4(acc[i], a.x, w0);
            fma4(acc[i], a.y, w1);
            fma4(acc[i], a.z, w2);
            fma4(acc[i], a.w, w3);
        }
    }

    const float4 bv = ((const float4*)b)[c];
#pragma unroll
    for (int i = 0; i < 8; ++i) {
        long n = base + i;
        if (n < NNODES) {
            float ci = c_in[n];
            float4 res;
            res.x = fmaf(acc[i].x, ci, bv.x);
            res.y = fmaf(acc[i].y, ci, bv.y);
            res.z = fmaf(acc[i].z, ci, bv.z);
            res.w = fmaf(acc[i].w, ci, bv.w);
            if (RELU) {
                res.x = fmaxf(res.x, 0.f);
                res.y = fmaxf(res.y, 0.f);
                res.z = fmaxf(res.z, 0.f);
                res.w = fmaxf(res.w, 0.f);
            }
            ((float4*)out)[n * (H / 4) + c] = res;
        }
    }
}

__global__ __launch_bounds__(512) void k_gemm1(const float* __restrict__ A,
                                               const float* __restrict__ c_in,
                                               const float* __restrict__ W,
                                               const float* __restrict__ b,
                                               float* __restrict__ out) {
    gemm_body<F0, true>(A, c_in, W, b, out);
}
__global__ __launch_bounds__(512) void k_gemm2(const float* __restrict__ A,
                                               const float* __restrict__ c_in,
                                               const float* __restrict__ W,
                                               const float* __restrict__ b,
                                               float* __restrict__ out) {
    gemm_body<H, true>(A, c_in, W, b, out);
}
__global__ __launch_bounds__(512) void k_gemm3(const float* __restrict__ A,
                                               const float* __restrict__ c_in,
                                               const float* __restrict__ W,
                                               const float* __restrict__ b,
                                               float* __restrict__ out) {
    gemm_body<H, false>(A, c_in, W, b, out);
}

// ---------------- fused graph head: readout mean + 3-layer MLP ----------------
// 1 block = 4 graphs; wave w owns graph blockIdx*4+w end-to-end (wave-private LDS,
// no barriers needed: each wave reads only what it wrote).
__global__ __launch_bounds__(256) void k_head(const float* __restrict__ y,
                                              const int* __restrict__ gstart,
                                              const float* __restrict__ fg,
                                              const float* __restrict__ Wl1,
                                              const float* __restrict__ bl1,
                                              const float* __restrict__ Wl2,
                                              const float* __restrict__ bl2,
                                              const float* __restrict__ Wl3,
                                              const float* __restrict__ bl3,
                                              float* __restrict__ out) {
    __shared__ float smean[4][H];
    __shared__ float sh1[4][H2];
    __shared__ float sh2[4][H2];

    const int w    = threadIdx.x >> 6;
    const int lane = threadIdx.x & 63;
    const int g    = blockIdx.x * 4 + w;

    // readout: segment mean (contiguous rows)
    {
        int beg = gstart[g], end = gstart[g + 1];
        const float2* y2 = (const float2*)y;
        float2 acc = make_float2(0.f, 0.f);
        for (int n = beg; n < end; ++n) {
            float2 v = y2[(long)n * 64 + lane];
            acc.x += v.x;
            acc.y += v.y;
        }
        float inv = 1.0f / fmaxf((float)(end - beg), 1.0f);
        ((float2*)smean[w])[lane] = make_float2(acc.x * inv, acc.y * inv);
    }

    // mlp1: 131 -> 256 (+relu). lane jq = float4 column quad.
    {
        float4 acc = ((const float4*)bl1)[lane];
        for (int k = 0; k < H; ++k)
            fma4(acc, smean[w][k], ((const float4*)(Wl1 + (long)k * H2))[lane]);
#pragma unroll
        for (int k = 0; k < 3; ++k)
            fma4(acc, fg[g * 3 + k], ((const float4*)(Wl1 + (long)(H + k) * H2))[lane]);
        acc.x = fmaxf(acc.x, 0.f); acc.y = fmaxf(acc.y, 0.f);
        acc.z = fmaxf(acc.z, 0.f); acc.w = fmaxf(acc.w, 0.f);
        ((float4*)sh1[w])[lane] = acc;
    }

    // mlp2: 256 -> 256 (+relu)
    {
        float4 acc = ((const float4*)bl2)[lane];
        for (int k = 0; k < H2; ++k)
            fma4(acc, sh1[w][k], ((const float4*)(Wl2 + (long)k * H2))[lane]);
        acc.x = fmaxf(acc.x, 0.f); acc.y = fmaxf(acc.y, 0.f);
        acc.z = fmaxf(acc.z, 0.f); acc.w = fmaxf(acc.w, 0.f);
        ((float4*)sh2[w])[lane] = acc;
    }

    // mlp3: 256 -> 1
    {
        float sum = sh2[w][lane] * Wl3[lane]
                  + sh2[w][lane + 64] * Wl3[lane + 64]
                  + sh2[w][lane + 128] * Wl3[lane + 128]
                  + sh2[w][lane + 192] * Wl3[lane + 192];
        for (int off = 32; off; off >>= 1)
            sum += __shfl_down(sum, off);
        if (lane == 0) out[g] = sum + bl3[0];
    }
}

extern "C" void kernel_launch(void* const* d_in, const int* in_sizes, int n_in,
                              void* d_out, int out_size, void* d_ws, size_t ws_size,
                              hipStream_t stream) {
    const float* feats_node  = (const float*)d_in[0];
    const float* feats_graph = (const float*)d_in[1];
    const float* W1 = (const float*)d_in[2];
    const float* b1 = (const float*)d_in[3];
    const float* W2 = (const float*)d_in[4];
    const float* b2 = (const float*)d_in[5];
    const float* W3 = (const float*)d_in[6];
    const float* b3 = (const float*)d_in[7];
    const float* Wl1 = (const float*)d_in[8];
    const float* bl1 = (const float*)d_in[9];
    const float* Wl2 = (const float*)d_in[10];
    const float* bl2 = (const float*)d_in[11];
    const float* Wl3 = (const float*)d_in[12];
    const float* bl3 = (const float*)d_in[13];
    const int* src  = (const int*)d_in[14];
    const int* dst  = (const int*)d_in[15];
    const int* gids = (const int*)d_in[16];
    float* out = (float*)d_out;

    // workspace layout (4B units)
    float* ws = (float*)d_ws;
    float* c_out     = ws;                        // 50048
    float* c_in      = c_out + 50048;             // 50048
    float* A         = c_in + 50048;              // N*H
    float* B         = A + (size_t)NNODES * H;    // N*H
    int*   row_start = (int*)(B + (size_t)NNODES * H);  // 50176
    int*   csr_src   = row_start + 50176;         // 600000
    int*   cursor    = csr_src + NEDGES;          // 50176
    int*   gstart    = cursor + 50176;            // 2048
    int*   partials  = gstart + 2048;             // 64
    int*   dout      = partials + 64;             // 50048
    int*   din       = dout + 50048;              // 50048

    // degrees (int)
    hipMemsetAsync(dout, 0, 2 * 50048 * sizeof(int), stream);
    k_deg<<<(NEDGES / 4 + 255) / 256, 256, 0, stream>>>(src, dst, dout, din);

    // CSR build (hierarchical scan) + fused cnorm + cursor zeroing
    k_scan1<<<NB, 1024, 0, stream>>>(din, row_start, partials, c_in);
    k_scan2<<<1, 64, 0, stream>>>(partials);
    k_scan3<<<NB, 1024, 0, stream>>>(row_start, partials, dout, c_out, cursor);
    k_fill<<<(NEDGES / 4 + 255) / 256, 256, 0, stream>>>(src, dst, row_start, cursor, csr_src);
    k_gbounds<<<(NNODES + 256) / 256, 256, 0, stream>>>(gids, gstart);

    const int GEMM_GRID = (NNODES + 127) / 128;

    // layer 1
    k_gather1<<<NNODES / 4, 256, 0, stream>>>(feats_node, c_out, row_start, csr_src, A);
    k_gemm1<<<GEMM_GRID, 512, 0, stream>>>(A, c_in, W1, b1, B);

    // layer 2
    k_gather2<<<NNODES / 4, 256, 0, stream>>>(B, c_out, row_start, csr_src, A);
    k_gemm2<<<GEMM_GRID, 512, 0, stream>>>(A, c_in, W2, b2, B);

    // layer 3 (no relu)
    k_gather3<<<NNODES / 4, 256, 0, stream>>>(B, c_out, row_start, csr_src, A);
    k_gemm3<<<GEMM_GRID, 512, 0, stream>>>(A, c_in, W3, b3, B);

    // fused head: readout mean + MLP
    k_head<<<NGRAPH / 4, 256, 0, stream>>>(B, gstart, feats_graph,
                                           Wl1, bl1, Wl2, bl2, Wl3, bl3, out);
}

// Round 8
// 407.101 us; speedup vs baseline: 7.5978x; 1.0529x over previous
//
#include <hip/hip_runtime.h>

constexpr int NNODES = 50000;
constexpr int NEDGES = 600000;
constexpr int NGRAPH = 2000;
constexpr int F0     = 64;    // IN_FEATS
constexpr int H      = 128;   // HIDDEN
constexpr int H2     = 256;   // 2*HIDDEN
constexpr int NB     = 49;    // scan blocks: 49*1024 >= 50000

static __device__ __forceinline__ void fma4(float4& acc, float s, const float4& w) {
    acc.x = fmaf(s, w.x, acc.x);
    acc.y = fmaf(s, w.y, acc.y);
    acc.z = fmaf(s, w.z, acc.z);
    acc.w = fmaf(s, w.w, acc.w);
}

// ---------------- degree count + per-edge rank (rank = slot within dst row) ----------------
__global__ void k_deg(const int* __restrict__ src, const int* __restrict__ dst,
                      int* __restrict__ dout, int* __restrict__ din,
                      int* __restrict__ rank) {
    int t = blockIdx.x * 256 + threadIdx.x;
    if (t * 4 >= NEDGES) return;
    int4 s4 = ((const int4*)src)[t];
    int4 d4 = ((const int4*)dst)[t];
    int4 r4;
    r4.x = atomicAdd(&din[d4.x], 1);
    r4.y = atomicAdd(&din[d4.y], 1);
    r4.z = atomicAdd(&din[d4.z], 1);
    r4.w = atomicAdd(&din[d4.w], 1);
    ((int4*)rank)[t] = r4;
    atomicAdd(&dout[s4.x], 1);
    atomicAdd(&dout[s4.y], 1);
    atomicAdd(&dout[s4.z], 1);
    atomicAdd(&dout[s4.w], 1);
}

// ---------------- scan phase 1: per-block scan of deg_in; also c_in ----------------
__global__ __launch_bounds__(1024) void k_scan1(const int* __restrict__ deg,
                                                int* __restrict__ row_start,
                                                int* __restrict__ partials,
                                                float* __restrict__ c_in) {
    __shared__ int wsum[16];
    int idx  = blockIdx.x * 1024 + threadIdx.x;
    int lane = threadIdx.x & 63;
    int wid  = threadIdx.x >> 6;
    int v = (idx < NNODES) ? deg[idx] : 0;
    if (idx < NNODES) c_in[idx] = rsqrtf(fmaxf((float)v, 1.0f));
    int incl = v;
#pragma unroll
    for (int off = 1; off < 64; off <<= 1) {
        int t = __shfl_up(incl, off);
        if (lane >= off) incl += t;
    }
    if (lane == 63) wsum[wid] = incl;
    __syncthreads();
    if (wid == 0) {
        int w = (lane < 16) ? wsum[lane] : 0;
        int wincl = w;
#pragma unroll
        for (int off = 1; off < 16; off <<= 1) {
            int t = __shfl_up(wincl, off);
            if (lane >= off) wincl += t;
        }
        if (lane < 16) wsum[lane] = wincl - w;
    }
    __syncthreads();
    int excl = wsum[wid] + incl - v;
    if (idx < NNODES) row_start[idx] = excl;
    if (threadIdx.x == 1023) partials[blockIdx.x] = excl + v;
}

// ---------------- scan phase 2 (fused): block offsets + sentinel + c_out + gbounds ----------------
// each block redundantly wave-scans the NB partials (cheap), picks its own offset.
__global__ __launch_bounds__(1024) void k_scan3(int* __restrict__ row_start,
                                                const int* __restrict__ partials,
                                                const int* __restrict__ dout,
                                                float* __restrict__ c_out,
                                                const int* __restrict__ gids,
                                                int* __restrict__ gstart) {
    __shared__ int soff[2];
    if (threadIdx.x < 64) {
        int lane = threadIdx.x;
        int v = (lane < NB) ? partials[lane] : 0;
        int incl = v;
#pragma unroll
        for (int off = 1; off < 64; off <<= 1) {
            int t = __shfl_up(incl, off);
            if (lane >= off) incl += t;
        }
        if (lane == (int)blockIdx.x) soff[0] = incl - v;  // exclusive offset
        if (lane == NB - 1) soff[1] = incl;               // grand total
    }
    __syncthreads();
    int idx = blockIdx.x * 1024 + threadIdx.x;
    if (idx < NNODES) {
        row_start[idx] += soff[0];
        c_out[idx] = rsqrtf(fmaxf((float)dout[idx], 1.0f));
    } else if (idx == NNODES) {
        row_start[NNODES] = soff[1];
    }
    // fused graph segment boundaries (sorted gids)
    if (idx == 0) {
        int g0 = gids[0];
        for (int g = 0; g <= g0; ++g) gstart[g] = 0;
    } else if (idx == NNODES) {
        int gl = gids[NNODES - 1];
        for (int g = gl + 1; g <= NGRAPH; ++g) gstart[g] = NNODES;
    } else if (idx < NNODES) {
        int a = gids[idx - 1], b = gids[idx];
        for (int g = a + 1; g <= b; ++g) gstart[g] = idx;
    }
}

// ---------------- fill CSR: atomic-free (rank precomputed) ----------------
__global__ void k_fill(const int* __restrict__ src, const int* __restrict__ dst,
                       const int* __restrict__ row_start, const int* __restrict__ rank,
                       int* __restrict__ csr_src) {
    int t = blockIdx.x * 256 + threadIdx.x;
    if (t * 4 >= NEDGES) return;
    int4 s4 = ((const int4*)src)[t];
    int4 d4 = ((const int4*)dst)[t];
    int4 r4 = ((const int4*)rank)[t];
    csr_src[row_start[d4.x] + r4.x] = s4.x;
    csr_src[row_start[d4.y] + r4.y] = s4.y;
    csr_src[row_start[d4.z] + r4.z] = s4.z;
    csr_src[row_start[d4.w] + r4.w] = s4.w;
}

// ---------------- gather: layer 1 (F=64, with c_out) ----------------
__global__ __launch_bounds__(256) void k_gather1(const float* __restrict__ x,
                                                 const float* __restrict__ c_out,
                                                 const int* __restrict__ row_start,
                                                 const int* __restrict__ csr_src,
                                                 float* __restrict__ agg) {
    int wid  = (blockIdx.x * 256 + threadIdx.x) >> 6;
    int lane = threadIdx.x & 63;
    if (wid >= NNODES) return;
    int beg = row_start[wid], end = row_start[wid + 1];
    float acc = 0.f;
#pragma unroll 4
    for (int i = beg; i < end; ++i) {
        int s = csr_src[i];
        acc += x[(long)s * F0 + lane] * c_out[s];
    }
    agg[(long)wid * F0 + lane] = acc;
}

// ---------------- gather: layers 2/3 (F=128, input pre-scaled by c_out) ----------------
static __device__ __forceinline__ void gather_h_body(const float* __restrict__ x,
                                                     const int* __restrict__ row_start,
                                                     const int* __restrict__ csr_src,
                                                     float* __restrict__ agg) {
    int wid  = (blockIdx.x * 256 + threadIdx.x) >> 6;
    int lane = threadIdx.x & 63;
    if (wid >= NNODES) return;
    int beg = row_start[wid], end = row_start[wid + 1];
    const float2* x2 = (const float2*)x;
    float2 acc = make_float2(0.f, 0.f);
#pragma unroll 4
    for (int i = beg; i < end; ++i) {
        int s = csr_src[i];
        float2 v = x2[(long)s * 64 + lane];
        acc.x += v.x;
        acc.y += v.y;
    }
    ((float2*)agg)[(long)wid * 64 + lane] = acc;
}

__global__ __launch_bounds__(256) void k_gather2(const float* __restrict__ x,
                                                 const int* __restrict__ row_start,
                                                 const int* __restrict__ csr_src,
                                                 float* __restrict__ agg) {
    gather_h_body(x, row_start, csr_src, agg);
}
__global__ __launch_bounds__(256) void k_gather3(const float* __restrict__ x,
                                                 const int* __restrict__ row_start,
                                                 const int* __restrict__ csr_src,
                                                 float* __restrict__ agg) {
    gather_h_body(x, row_start, csr_src, agg);
}

// ---------------- register-blocked fused GEMM ----------------
// out[n][j] = act( c_in[n]*(A@W)[n][j] + b[j] ) * (COSCALE ? c_out[n] : 1)
template <int K, bool RELU, bool COSCALE>
static __device__ __forceinline__ void gemm_body(const float* __restrict__ A,
                                                 const float* __restrict__ c_in,
                                                 const float* __restrict__ c_out,
                                                 const float* __restrict__ W,
                                                 const float* __restrict__ b,
                                                 float* __restrict__ out) {
    __shared__ float sW[K * H];
    for (int i = threadIdx.x; i < K * (H / 4); i += 512)
        ((float4*)sW)[i] = ((const float4*)W)[i];
    __syncthreads();

    const int c = threadIdx.x & 31;
    const int r = threadIdx.x >> 5;
    const long base = (long)blockIdx.x * 128 + r * 8;

    float4 acc[8];
#pragma unroll
    for (int i = 0; i < 8; ++i) acc[i] = make_float4(0.f, 0.f, 0.f, 0.f);

    const float4* Ap = (const float4*)A + base * (K / 4);

    for (int k4 = 0; k4 < K / 4; ++k4) {
        const float4 w0 = *(const float4*)&sW[(4 * k4 + 0) * H + 4 * c];
        const float4 w1 = *(const float4*)&sW[(4 * k4 + 1) * H + 4 * c];
        const float4 w2 = *(const float4*)&sW[(4 * k4 + 2) * H + 4 * c];
        const float4 w3 = *(const float4*)&sW[(4 * k4 + 3) * H + 4 * c];
#pragma unroll
        for (int i = 0; i < 8; ++i) {
            float4 a = Ap[(long)i * (K / 4) + k4];
            fma4(acc[i], a.x, w0);
            fma4(acc[i], a.y, w1);
            fma4(acc[i], a.z, w2);
            fma4(acc[i], a.w, w3);
        }
    }

    const float4 bv = ((const float4*)b)[c];
#pragma unroll
    for (int i = 0; i < 8; ++i) {
        long n = base + i;
        if (n < NNODES) {
            float ci = c_in[n];
            float4 res;
            res.x = fmaf(acc[i].x, ci, bv.x);
            res.y = fmaf(acc[i].y, ci, bv.y);
            res.z = fmaf(acc[i].z, ci, bv.z);
            res.w = fmaf(acc[i].w, ci, bv.w);
            if (RELU) {
                res.x = fmaxf(res.x, 0.f);
                res.y = fmaxf(res.y, 0.f);
                res.z = fmaxf(res.z, 0.f);
                res.w = fmaxf(res.w, 0.f);
            }
            if (COSCALE) {
                float co = c_out[n];
                res.x *= co; res.y *= co; res.z *= co; res.w *= co;
            }
            ((float4*)out)[n * (H / 4) + c] = res;
        }
    }
}

__global__ __launch_bounds__(512) void k_gemm1(const float* __restrict__ A,
                                               const float* __restrict__ c_in,
                                               const float* __restrict__ c_out,
                                               const float* __restrict__ W,
                                               const float* __restrict__ b,
                                               float* __restrict__ out) {
    gemm_body<F0, true, true>(A, c_in, c_out, W, b, out);
}
__global__ __launch_bounds__(512) void k_gemm2(const float* __restrict__ A,
                                               const float* __restrict__ c_in,
                                               const float* __restrict__ c_out,
                                               const float* __restrict__ W,
                                               const float* __restrict__ b,
                                               float* __restrict__ out) {
    gemm_body<H, true, true>(A, c_in, c_out, W, b, out);
}
__global__ __launch_bounds__(512) void k_gemm3(const float* __restrict__ A,
                                               const float* __restrict__ c_in,
                                               const float* __restrict__ c_out,
                                               const float* __restrict__ W,
                                               const float* __restrict__ b,
                                               float* __restrict__ out) {
    gemm_body<H, false, false>(A, c_in, c_out, W, b, out);
}

// ---------------- fused graph head: readout mean + 3-layer MLP ----------------
// 1 block = 8 graphs; wave w owns graph blockIdx*8+w (wave-private LDS, no barriers).
__global__ __launch_bounds__(512) void k_head(const float* __restrict__ y,
                                              const int* __restrict__ gstart,
                                              const float* __restrict__ fg,
                                              const float* __restrict__ Wl1,
                                              const float* __restrict__ bl1,
                                              const float* __restrict__ Wl2,
                                              const float* __restrict__ bl2,
                                              const float* __restrict__ Wl3,
                                              const float* __restrict__ bl3,
                                              float* __restrict__ out) {
    __shared__ float smean[8][H];
    __shared__ float sh1[8][H2];
    __shared__ float sh2[8][H2];

    const int w    = threadIdx.x >> 6;
    const int lane = threadIdx.x & 63;
    const int g    = blockIdx.x * 8 + w;

    // readout: segment mean (contiguous rows)
    {
        int beg = gstart[g], end = gstart[g + 1];
        const float2* y2 = (const float2*)y;
        float2 acc = make_float2(0.f, 0.f);
        for (int n = beg; n < end; ++n) {
            float2 v = y2[(long)n * 64 + lane];
            acc.x += v.x;
            acc.y += v.y;
        }
        float inv = 1.0f / fmaxf((float)(end - beg), 1.0f);
        ((float2*)smean[w])[lane] = make_float2(acc.x * inv, acc.y * inv);
    }

    // mlp1: 131 -> 256 (+relu)
    {
        float4 acc = ((const float4*)bl1)[lane];
        for (int k = 0; k < H; ++k)
            fma4(acc, smean[w][k], ((const float4*)(Wl1 + (long)k * H2))[lane]);
#pragma unroll
        for (int k = 0; k < 3; ++k)
            fma4(acc, fg[g * 3 + k], ((const float4*)(Wl1 + (long)(H + k) * H2))[lane]);
        acc.x = fmaxf(acc.x, 0.f); acc.y = fmaxf(acc.y, 0.f);
        acc.z = fmaxf(acc.z, 0.f); acc.w = fmaxf(acc.w, 0.f);
        ((float4*)sh1[w])[lane] = acc;
    }

    // mlp2: 256 -> 256 (+relu)
    {
        float4 acc = ((const float4*)bl2)[lane];
        for (int k = 0; k < H2; ++k)
            fma4(acc, sh1[w][k], ((const float4*)(Wl2 + (long)k * H2))[lane]);
        acc.x = fmaxf(acc.x, 0.f); acc.y = fmaxf(acc.y, 0.f);
        acc.z = fmaxf(acc.z, 0.f); acc.w = fmaxf(acc.w, 0.f);
        ((float4*)sh2[w])[lane] = acc;
    }

    // mlp3: 256 -> 1
    {
        float sum = sh2[w][lane] * Wl3[lane]
                  + sh2[w][lane + 64] * Wl3[lane + 64]
                  + sh2[w][lane + 128] * Wl3[lane + 128]
                  + sh2[w][lane + 192] * Wl3[lane + 192];
        for (int off = 32; off; off >>= 1)
            sum += __shfl_down(sum, off);
        if (lane == 0) out[g] = sum + bl3[0];
    }
}

extern "C" void kernel_launch(void* const* d_in, const int* in_sizes, int n_in,
                              void* d_out, int out_size, void* d_ws, size_t ws_size,
                              hipStream_t stream) {
    const float* feats_node  = (const float*)d_in[0];
    const float* feats_graph = (const float*)d_in[1];
    const float* W1 = (const float*)d_in[2];
    const float* b1 = (const float*)d_in[3];
    const float* W2 = (const float*)d_in[4];
    const float* b2 = (const float*)d_in[5];
    const float* W3 = (const float*)d_in[6];
    const float* b3 = (const float*)d_in[7];
    const float* Wl1 = (const float*)d_in[8];
    const float* bl1 = (const float*)d_in[9];
    const float* Wl2 = (const float*)d_in[10];
    const float* bl2 = (const float*)d_in[11];
    const float* Wl3 = (const float*)d_in[12];
    const float* bl3 = (const float*)d_in[13];
    const int* src  = (const int*)d_in[14];
    const int* dst  = (const int*)d_in[15];
    const int* gids = (const int*)d_in[16];
    float* out = (float*)d_out;

    // workspace layout (4B units)
    float* ws = (float*)d_ws;
    float* c_out     = ws;                        // 50048
    float* c_in      = c_out + 50048;             // 50048
    float* A         = c_in + 50048;              // N*H
    float* B         = A + (size_t)NNODES * H;    // N*H
    int*   row_start = (int*)(B + (size_t)NNODES * H);  // 50176
    int*   csr_src   = row_start + 50176;         // 600000
    int*   gstart    = csr_src + NEDGES;          // 2048
    int*   partials  = gstart + 2048;             // 64
    int*   dout      = partials + 64;             // 50048
    int*   din       = dout + 50048;              // 50048
    int*   rank      = (int*)A;                   // aliases A: consumed by k_fill before gather1 writes A

    // degrees + edge ranks
    hipMemsetAsync(dout, 0, 2 * 50048 * sizeof(int), stream);
    k_deg<<<(NEDGES / 4 + 255) / 256, 256, 0, stream>>>(src, dst, dout, din, rank);

    // CSR offsets (scan1 + fused scan3: offsets, c_out, gbounds) + atomic-free fill
    k_scan1<<<NB, 1024, 0, stream>>>(din, row_start, partials, c_in);
    k_scan3<<<NB, 1024, 0, stream>>>(row_start, partials, dout, c_out, gids, gstart);
    k_fill<<<(NEDGES / 4 + 255) / 256, 256, 0, stream>>>(src, dst, row_start, rank, csr_src);

    const int GEMM_GRID = (NNODES + 127) / 128;

    // layer 1 (gather applies c_out; gemm epilogue pre-scales output by c_out)
    k_gather1<<<NNODES / 4, 256, 0, stream>>>(feats_node, c_out, row_start, csr_src, A);
    k_gemm1<<<GEMM_GRID, 512, 0, stream>>>(A, c_in, c_out, W1, b1, B);

    // layer 2 (input pre-scaled; epilogue pre-scales again for layer 3)
    k_gather2<<<NNODES / 4, 256, 0, stream>>>(B, row_start, csr_src, A);
    k_gemm2<<<GEMM_GRID, 512, 0, stream>>>(A, c_in, c_out, W2, b2, B);

    // layer 3 (no relu, no pre-scale)
    k_gather3<<<NNODES / 4, 256, 0, stream>>>(B, row_start, csr_src, A);
    k_gemm3<<<GEMM_GRID, 512, 0, stream>>>(A, c_in, c_out, W3, b3, B);

    // fused head: readout mean + MLP
    k_head<<<NGRAPH / 8, 512, 0, stream>>>(B, gstart, feats_graph,
                                           Wl1, bl1, Wl2, bl2, Wl3, bl3, out);
}